// Round 11
// baseline (8040.852 us; speedup 1.0000x reference)
//
#include <hip/hip_runtime.h>

// ---------------- problem constants ----------------
#define NB 8          // meta-batch (tasks)
#define NT 5          // inner steps
#define NL 16         // test examples per task
#define NCLS 100
#define FEAT 4096
#define CHW (3*64*64) // 12288

// per-task fast-weight block offsets (floats)
#define OFF_W0 0
#define OFF_B0 864
#define OFF_W1 896
#define OFF_B1 19328
#define OFF_W2 19392
#define OFF_B2 93120
#define OFF_W3 93248
#define OFF_B3 388160
#define OFF_W4 388416
#define OFF_B4 978240
#define OFF_WO 978496
#define OFF_BO 1388096
#define PT     1388196   // floats per task

// per-task inner activation block offsets (floats)
#define A1 0          // 32*64*64 = 131072
#define A2 131072     // 64*32*32 =  65536
#define A3 196608     // 128*16*16 = 32768
#define A4 229376     // 256*8*8  =  16384
#define A5 245760     // 256*4*4  =   4096
#define ATOT 249856

struct Params12 { const float* p[12]; };

// ---------------- broadcast initial params to per-task fast weights ----------------
__global__ void bcast_kernel(Params12 ps, float* __restrict__ fw) {
    const int offs[13] = {OFF_W0,OFF_B0,OFF_W1,OFF_B1,OFF_W2,OFF_B2,OFF_W3,OFF_B3,
                          OFF_W4,OFF_B4,OFF_WO,OFF_BO,PT};
    long idx = (long)blockIdx.x * blockDim.x + threadIdx.x;
    long total = (long)NB * PT;
    if (idx >= total) return;
    int i = (int)(idx % PT);
    int j = 11;
    while (j > 0 && i < offs[j]) --j;
    fw[idx] = ps.p[j][i - offs[j]];
}

// ---------------- generic direct conv fwd + bias + relu (proven) ----------------
__global__ void conv_fwd(const float* __restrict__ xb, long x_ts, long x_es,
                         const float* __restrict__ fw, int woff, int boff,
                         float* __restrict__ yb, long y_ts,
                         int N, int IC, int IH, int IW, int OC, int OH, int OW, int s)
{
    long idx = (long)blockIdx.x * blockDim.x + threadIdx.x;
    long total = (long)NB * N * OC * OH * OW;
    if (idx >= total) return;
    int ow = (int)(idx % OW); long r = idx / OW;
    int oh = (int)(r % OH); r /= OH;
    int oc = (int)(r % OC); r /= OC;
    int n  = (int)(r % N);  int b = (int)(r / N);

    const float* x = xb + (long)b * x_ts + (long)n * x_es;
    const float* w = fw + (long)b * PT + woff + (long)oc * IC * 9;
    float acc = fw[(long)b * PT + boff + oc];
    int ih0 = oh * s - 1, iw0 = ow * s - 1;
    for (int ic = 0; ic < IC; ++ic) {
        const float* xc = x + (long)ic * IH * IW;
        const float* wc = w + ic * 9;
        #pragma unroll
        for (int kh = 0; kh < 3; ++kh) {
            int ih = ih0 + kh;
            if (ih < 0 || ih >= IH) continue;
            #pragma unroll
            for (int kw = 0; kw < 3; ++kw) {
                int iw = iw0 + kw;
                if (iw < 0 || iw >= IW) continue;
                acc += xc[ih * IW + iw] * wc[kh * 3 + kw];
            }
        }
    }
    yb[(long)b * y_ts + (((long)n * OC + oc) * OH + oh) * OW + ow] = fmaxf(acc, 0.f);
}

// ---------------- train-path conv: conv_fwd mapping + UF-blocked loads (proven r7) ----------------
template<int IC,int IH,int IW,int OC,int OH,int OW,int S,int UF>
__global__ __launch_bounds__(256) void conv_fwd_u(
    const float* __restrict__ xb, long x_ts,
    const float* __restrict__ fw, int woff, int boff,
    float* __restrict__ yb, long y_ts)
{
    constexpr int OHW = OH*OW, IHW = IH*IW;
    long idx = (long)blockIdx.x * 256 + threadIdx.x;
    int pix = (int)(idx % OHW); long r = idx / OHW;
    int oc = (int)(r % OC); int b = (int)(r / OC);
    int oh = pix / OW, ow = pix % OW;
    int ih0 = oh*S - 1, iw0 = ow*S - 1;

    const float* x = xb + (long)b * x_ts;
    const float* w = fw + (long)b * PT + woff + (long)oc * IC * 9;
    float acc = fw[(long)b * PT + boff + oc];

    #pragma unroll 1
    for (int ic0 = 0; ic0 < IC; ic0 += UF) {
        float xv[UF][9];
        #pragma unroll
        for (int u = 0; u < UF; ++u) {
            const float* xc = x + (long)(ic0 + u) * IHW;
            #pragma unroll
            for (int kh = 0; kh < 3; ++kh) {
                int ih = ih0 + kh;
                #pragma unroll
                for (int kw = 0; kw < 3; ++kw) {
                    int iw = iw0 + kw;
                    bool v = ((unsigned)ih < (unsigned)IH) && ((unsigned)iw < (unsigned)IW);
                    xv[u][kh*3+kw] = v ? xc[ih*IW + iw] : 0.f;
                }
            }
        }
        #pragma unroll
        for (int u = 0; u < UF; ++u) {
            const float* wc = w + (ic0 + u) * 9;
            #pragma unroll
            for (int k = 0; k < 9; ++k)
                acc += xv[u][k] * wc[k];
        }
    }
    yb[(long)b * y_ts + (long)oc * OHW + pix] = fmaxf(acc, 0.f);
}

// ---------------- per-thread-output conv with n axis (test deep layers, under test) ----------
// Same body/accumulation order as conv_fwd_u; idx -> (pix, oc, n, b). Grid = NB*N*OC*OHW/256.
template<int IC,int IH,int IW,int OC,int OH,int OW,int S,int UF,int N>
__global__ __launch_bounds__(256) void conv_fwd_un(
    const float* __restrict__ xb, long x_ts, long x_es,
    const float* __restrict__ fw, int woff, int boff,
    float* __restrict__ yb, long y_ts)
{
    constexpr int OHW = OH*OW, IHW = IH*IW;
    long idx = (long)blockIdx.x * 256 + threadIdx.x;
    int pix = (int)(idx % OHW); long r = idx / OHW;
    int oc = (int)(r % OC); r /= OC;
    int n  = (int)(r % N);  int b = (int)(r / N);
    int oh = pix / OW, ow = pix % OW;
    int ih0 = oh*S - 1, iw0 = ow*S - 1;

    const float* x = xb + (long)b * x_ts + (long)n * x_es;
    const float* w = fw + (long)b * PT + woff + (long)oc * IC * 9;
    float acc = fw[(long)b * PT + boff + oc];

    #pragma unroll 1
    for (int ic0 = 0; ic0 < IC; ic0 += UF) {
        float xv[UF][9];
        #pragma unroll
        for (int u = 0; u < UF; ++u) {
            const float* xc = x + (long)(ic0 + u) * IHW;
            #pragma unroll
            for (int kh = 0; kh < 3; ++kh) {
                int ih = ih0 + kh;
                #pragma unroll
                for (int kw = 0; kw < 3; ++kw) {
                    int iw = iw0 + kw;
                    bool v = ((unsigned)ih < (unsigned)IH) && ((unsigned)iw < (unsigned)IW);
                    xv[u][kh*3+kw] = v ? xc[ih*IW + iw] : 0.f;
                }
            }
        }
        #pragma unroll
        for (int u = 0; u < UF; ++u) {
            const float* wc = w + (ic0 + u) * 9;
            #pragma unroll
            for (int k = 0; k < 9; ++k)
                acc += xv[u][k] * wc[k];
        }
    }
    yb[(long)b * y_ts + ((long)n * OC + oc) * OHW + pix] = fmaxf(acc, 0.f);
}

// ---------------- tiled conv fwd (test path, shallow layers) — proven r5 ----------------
template<int IC,int IH,int IW,int OC,int OH,int OW,int S,int TOC,int NSUB,int ICB>
__global__ __launch_bounds__(256) void conv_fwd2(
    const float* __restrict__ xb, long x_ts, long x_es,
    const float* __restrict__ fw, int woff, int boff,
    float* __restrict__ yb, long y_ts, int N)
{
    constexpr int OHW = OH*OW, IHW = IH*IW;
    constexpr int PPB = 256/NSUB;          // pixels per block
    constexpr int TILES = OHW/PPB;         // spatial tiles
    constexpr int OCB = NSUB*TOC;          // ocs per block
    constexpr int NOCG = OC/OCB;
    __shared__ float wlds[ICB*9*OCB];      // [icb][k][ocb]

    int bi = blockIdx.x;
    int tile = bi % TILES;
    int ocg  = (bi / TILES) % NOCG;
    int n    = (bi / (TILES*NOCG)) % N;
    int b    = bi / (TILES*NOCG*N);

    int tid = threadIdx.x;
    int pixl = tid % PPB, sub = tid / PPB;
    int pix = tile * PPB + pixl;
    int oc0 = ocg * OCB + sub * TOC;
    int oh = pix / OW, ow = pix % OW;
    int ih0 = oh*S - 1, iw0 = ow*S - 1;

    const float* xp  = xb + (long)b * x_ts + (long)n * x_es;
    const float* fwp = fw + (long)b * PT + woff;
    const float* bp  = fw + (long)b * PT + boff;

    float acc[TOC];
    #pragma unroll
    for (int t = 0; t < TOC; ++t) acc[t] = bp[oc0 + t];

    #pragma unroll 1
    for (int ic0i = 0; ic0i < IC; ic0i += ICB) {
        __syncthreads();
        for (int i = tid; i < ICB*9*OCB; i += 256) {
            int o = i % OCB; int rem = i / OCB; int k = rem % 9; int icb = rem / 9;
            wlds[i] = fwp[((long)(ocg*OCB + o) * IC + ic0i + icb) * 9 + k];
        }
        __syncthreads();
        #pragma unroll 2
        for (int icb = 0; icb < ICB; ++icb) {
            const float* xc = xp + (long)(ic0i + icb) * IHW;
            float xv[9];
            #pragma unroll
            for (int kh = 0; kh < 3; ++kh)
            #pragma unroll
            for (int kw = 0; kw < 3; ++kw) {
                int ih = ih0 + kh, iw = iw0 + kw;
                bool v = ((unsigned)ih < (unsigned)IH) && ((unsigned)iw < (unsigned)IW);
                xv[kh*3+kw] = v ? xc[ih*IW + iw] : 0.f;
            }
            const float* wl = wlds + icb*9*OCB + sub*TOC;
            #pragma unroll
            for (int k = 0; k < 9; ++k) {
                #pragma unroll
                for (int t = 0; t < TOC; ++t)
                    acc[t] += xv[k] * wl[k*OCB + t];
            }
        }
    }

    float* yp = yb + (long)b * y_ts;
    #pragma unroll
    for (int t = 0; t < TOC; ++t)
        yp[((long)n*OC + oc0 + t) * OHW + pix] = fmaxf(acc[t], 0.f);
}

// ---------------- head forward ----------------
__global__ void head_fwd(const float* __restrict__ a5b, long a_ts, long a_es,
                         const float* __restrict__ gb, long g_ts, long g_es,
                         const float* __restrict__ fw,
                         float* __restrict__ ob, long o_ts, long o_es, int N)
{
    int wid = (int)(((long)blockIdx.x * blockDim.x + threadIdx.x) >> 6);
    int lane = threadIdx.x & 63;
    int total = NB * N * NCLS;
    if (wid >= total) return;
    int cls = wid % NCLS; int r = wid / NCLS;
    int n = r % N; int b = r / N;
    const float* a5 = a5b + (long)b * a_ts + (long)n * a_es;
    const float* g  = gb  + (long)b * g_ts + (long)n * g_es;
    const float* W  = fw + (long)b * PT + OFF_WO + (long)cls * FEAT;
    float acc = 0.f;
    for (int m = lane; m < FEAT; m += 64) acc += W[m] * a5[m] * g[m];
    for (int off = 32; off; off >>= 1) acc += __shfl_down(acc, off, 64);
    if (lane == 0)
        ob[(long)b * o_ts + (long)n * o_es + cls] = acc + fw[(long)b * PT + OFF_BO + cls];
}

// ---------------- inner softmax -> dlogit ----------------
__global__ void softmax_dlogit(const float* __restrict__ logi, const int* __restrict__ ty, int t,
                               float* __restrict__ dlog)
{
    __shared__ float red[128];
    int b = blockIdx.x, tid = threadIdx.x;
    const float* lo = logi + b * NCLS;
    float v = (tid < NCLS) ? lo[tid] : -1e30f;
    red[tid] = v; __syncthreads();
    for (int s2 = 64; s2; s2 >>= 1) { if (tid < s2) red[tid] = fmaxf(red[tid], red[tid + s2]); __syncthreads(); }
    float mx = red[0]; __syncthreads();
    float e = (tid < NCLS) ? expf(v - mx) : 0.f;
    red[tid] = e; __syncthreads();
    for (int s2 = 64; s2; s2 >>= 1) { if (tid < s2) red[tid] += red[tid + s2]; __syncthreads(); }
    float sum = red[0];
    if (tid < NCLS) {
        int y = ty[b * NT + t];
        dlog[b * NCLS + tid] = e / sum - (tid == y ? 1.f : 0.f);
    }
}

// ---------------- head backward: dz5 ----------------
__global__ void head_bwd_dz5(const float* __restrict__ fw, const float* __restrict__ dlog,
                             const float* __restrict__ ain, const float* __restrict__ gb, long g_ts,
                             float* __restrict__ dz)
{
    int idx = blockIdx.x * blockDim.x + threadIdx.x;
    if (idx >= NB * FEAT) return;
    int m = idx % FEAT, b = idx / FEAT;
    const float* W = fw + (long)b * PT + OFF_WO;
    float df = 0.f;
    for (int c = 0; c < NCLS; ++c) df += W[(long)c * FEAT + m] * dlog[b * NCLS + c];
    float a = ain[(long)b * ATOT + A5 + m];
    dz[(long)b * ATOT + A5 + m] = (a > 0.f) ? df * gb[(long)b * g_ts + m] : 0.f;
}

// ---------------- head update ----------------
__global__ void head_update(float* __restrict__ fw, const float* __restrict__ dlog,
                            const float* __restrict__ ain, const float* __restrict__ gb, long g_ts,
                            const float* __restrict__ loglr)
{
    long idx = (long)blockIdx.x * blockDim.x + threadIdx.x;
    long total = (long)NB * NCLS * FEAT;
    if (idx >= total) return;
    int m = (int)(idx % FEAT); long r = idx / FEAT;
    int c = (int)(r % NCLS); int b = (int)(r / NCLS);
    float lr = expf(loglr[0]);
    float f = ain[(long)b * ATOT + A5 + m] * gb[(long)b * g_ts + m];
    float dl = dlog[b * NCLS + c];
    fw[(long)b * PT + OFF_WO + (long)c * FEAT + m] -= lr * dl * f;
    if (m == 0) fw[(long)b * PT + OFF_BO + c] -= lr * dl;
}

// ---------------- conv backward dX (stride-2, parity taps, LDS weights) — r9 exact ----------------
template<int IC,int IH,int IW,int OC,int OH,int OW,int ICG,int BLK>
__global__ __launch_bounds__(BLK) void conv_bwd_dx2(
    const float* __restrict__ dzbuf, int dz_off,
    const float* __restrict__ fw, int woff,
    const float* __restrict__ ain, int ain_off,
    float* __restrict__ dzin, int dzin_off)
{
    constexpr int IHW = IH*IW, OHW = OH*OW, NICG = IC/ICG, PB = IHW/BLK;
    __shared__ float wlds[OC*9*ICG];   // [oc][k][g]
    int bi = blockIdx.x;
    int pb  = bi % PB;
    int icg = (bi / PB) % NICG;
    int b   = bi / (PB * NICG);
    int ic0 = icg * ICG;
    const float* fwp = fw + (long)b * PT + woff;
    for (int i = threadIdx.x; i < OC*9*ICG; i += BLK) {
        int g = i % ICG; int rem = i / ICG; int k = rem % 9; int oc = rem / 9;
        wlds[i] = fwp[((long)oc * IC + ic0 + g) * 9 + k];
    }
    __syncthreads();

    int pix = pb * BLK + threadIdx.x;
    int ih = pix / IW, iw = pix % IW;
    int kh0 = (ih + 1) & 1, kw0 = (iw + 1) & 1;
    int ohA = (ih + 1 - kh0) >> 1, owA = (iw + 1 - kw0) >> 1;
    float mhA = (ohA < OH) ? 1.f : 0.f;   float mhB = (kh0 == 0) ? 1.f : 0.f;
    float mwA = (owA < OW) ? 1.f : 0.f;   float mwB = (kw0 == 0) ? 1.f : 0.f;
    int ohB = ohA - 1, owB = owA - 1;
    int ohAc = (ohA < OH) ? ohA : 0;  int owAc = (owA < OW) ? owA : 0;
    int ohBc = (ohB >= 0) ? ohB : 0;  int owBc = (owB >= 0) ? owB : 0;

    int oAA = ohAc*OW + owAc; float mAA = mhA*mwA; int kAA = kh0*3 + kw0;
    int oAB = ohAc*OW + owBc; float mAB = mhA*mwB; int kAB = kh0*3 + kw0 + 2;
    int oBA = ohBc*OW + owAc; float mBA = mhB*mwA; int kBA = (kh0+2)*3 + kw0;
    int oBB = ohBc*OW + owBc; float mBB = mhB*mwB; int kBB = (kh0+2)*3 + kw0 + 2;

    const float* dzp = dzbuf + (long)b * ATOT + dz_off;
    float acc[ICG];
    #pragma unroll
    for (int g = 0; g < ICG; ++g) acc[g] = 0.f;

    for (int oc = 0; oc < OC; ++oc) {
        const float* dzo = dzp + oc * OHW;
        float dAA = dzo[oAA] * mAA;
        float dAB = dzo[oAB] * mAB;
        float dBA = dzo[oBA] * mBA;
        float dBB = dzo[oBB] * mBB;
        const float* w = wlds + oc * 9 * ICG;
        #pragma unroll
        for (int g = 0; g < ICG; ++g)
            acc[g] += dAA * w[kAA*ICG+g] + dAB * w[kAB*ICG+g]
                    + dBA * w[kBA*ICG+g] + dBB * w[kBB*ICG+g];
    }
    #pragma unroll
    for (int g = 0; g < ICG; ++g) {
        long p = (long)b * ATOT + (long)(ic0 + g) * IHW + pix;
        float a = ain[p + ain_off];
        dzin[p + dzin_off] = (a > 0.f) ? acc[g] : 0.f;
    }
}

// ---------------- conv backward dW+db: one wave per (b, oc, ic) ----------------
template<int IC,int IH,int IW,int OC,int OH,int OW,int S>
__global__ __launch_bounds__(64) void conv_bwd_dw2(
    float* __restrict__ fw, int woff, int boff,
    const float* __restrict__ dzbuf, int dz_off,
    const float* __restrict__ xb, long x_ts,
    const float* __restrict__ loglr)
{
    constexpr int OHW = OH*OW;
    int bi = blockIdx.x;
    int ic = bi % IC; int oc = (bi / IC) % OC; int b = bi / (IC * OC);
    int lane = threadIdx.x;
    const float* dzp = dzbuf + (long)b * ATOT + dz_off + (long)oc * OHW;
    const float* xp  = xb + (long)b * x_ts + (long)ic * IH * IW;

    float acc[10];
    #pragma unroll
    for (int k = 0; k < 10; ++k) acc[k] = 0.f;

    for (int pos = lane; pos < OHW; pos += 64) {
        float dzv = dzp[pos];
        int oh = pos / OW, ow = pos % OW;
        int ihb = oh * S - 1, iwb = ow * S - 1;
        acc[9] += dzv;
        #pragma unroll
        for (int kh = 0; kh < 3; ++kh) {
            int ih = ihb + kh;
            bool hv = ((unsigned)ih < (unsigned)IH);
            #pragma unroll
            for (int kw = 0; kw < 3; ++kw) {
                int iw = iwb + kw;
                float xv = (hv && (unsigned)iw < (unsigned)IW) ? xp[ih * IW + iw] : 0.f;
                acc[kh*3+kw] += dzv * xv;
            }
        }
    }
    #pragma unroll
    for (int k = 0; k < 10; ++k)
        for (int off = 32; off; off >>= 1) acc[k] += __shfl_down(acc[k], off, 64);

    if (lane == 0) {
        float lr = expf(loglr[0]);
        float* wp = fw + (long)b * PT + woff + ((long)oc * IC + ic) * 9;
        #pragma unroll
        for (int k = 0; k < 9; ++k) wp[k] -= lr * acc[k];
        if (ic == 0) fw[(long)b * PT + boff + oc] -= lr * acc[9];
    }
}

// ---------------- old dW/db (layer 4: tiny spatial) ----------------
__global__ void conv_bwd_dw(float* __restrict__ fw, int woff,
                            const float* __restrict__ dz, long dz_off,
                            const float* __restrict__ xb, long x_ts,
                            const float* __restrict__ loglr,
                            int IC, int IH, int IW, int OC, int OH, int OW, int s)
{
    long idx = (long)blockIdx.x * blockDim.x + threadIdx.x;
    long total = (long)NB * OC * IC * 9;
    if (idx >= total) return;
    int k = (int)(idx % 9); int kw = k % 3, kh = k / 3;
    long r = idx / 9; int ic = (int)(r % IC); r /= IC;
    int oc = (int)(r % OC); int b = (int)(r / OC);
    const float* dzp = dz + (long)b * ATOT + dz_off + (long)oc * OH * OW;
    const float* x = xb + (long)b * x_ts + (long)ic * IH * IW;
    float acc = 0.f;
    for (int oh = 0; oh < OH; ++oh) {
        int ih = oh * s - 1 + kh;
        if (ih < 0 || ih >= IH) continue;
        for (int ow = 0; ow < OW; ++ow) {
            int iw = ow * s - 1 + kw;
            if (iw < 0 || iw >= IW) continue;
            acc += dzp[oh * OW + ow] * x[ih * IW + iw];
        }
    }
    fw[(long)b * PT + woff + ((long)(oc * IC + ic) * 3 + kh) * 3 + kw] -= expf(loglr[0]) * acc;
}

__global__ void conv_bwd_db(float* __restrict__ fw, int boff,
                            const float* __restrict__ dz, long dz_off,
                            const float* __restrict__ loglr, int OC, int OH, int OW)
{
    int idx = blockIdx.x * blockDim.x + threadIdx.x;
    if (idx >= NB * OC) return;
    int oc = idx % OC, b = idx / OC;
    const float* p = dz + (long)b * ATOT + dz_off + (long)oc * OH * OW;
    float acc = 0.f;
    for (int i = 0; i < OH * OW; ++i) acc += p[i];
    fw[(long)b * PT + boff + oc] -= expf(loglr[0]) * acc;
}

// ---------------- final loss / eval ----------------
__global__ void final_loss_eval(const float* __restrict__ logit_base,
                                const int* __restrict__ test_y,
                                float* __restrict__ out, int l0, int Lc)
{
    int idx = blockIdx.x * blockDim.x + threadIdx.x;
    if (idx >= NB * Lc) return;
    int n = idx % Lc, b = idx / Lc;
    int l = l0 + n;
    const float* lo = logit_base + ((long)b * NL + l) * NCLS;
    float mx = -1e30f; int am = 0;
    for (int c = 0; c < NCLS; ++c) { float v = lo[c]; if (v > mx) { mx = v; am = c; } }
    float se = 0.f;
    for (int c = 0; c < NCLS; ++c) se += expf(lo[c] - mx);
    int y = test_y[b * NL + l];
    out[b * NL + l] = -(lo[y] - mx - logf(se));
    out[129 + b * NL + l] = (am == y) ? 1.f : 0.f;
}

__global__ void write_lr(const float* __restrict__ loglr, float* __restrict__ out)
{
    if (threadIdx.x == 0 && blockIdx.x == 0) out[128] = expf(loglr[0]);
}

// ---------------- host orchestration ----------------
extern "C" void kernel_launch(void* const* d_in, const int* in_sizes, int n_in,
                              void* d_out, int out_size, void* d_ws, size_t ws_size,
                              hipStream_t stream)
{
    const float* loglr      = (const float*)d_in[12];
    const float* train_x    = (const float*)d_in[13];
    const float* test_x     = (const float*)d_in[14];
    const float* train_gate = (const float*)d_in[15];
    const float* test_gate  = (const float*)d_in[16];
    const int*   train_y    = (const int*)d_in[17];
    const int*   test_y     = (const int*)d_in[18];
    float* out = (float*)d_out;

    // ---- choose test-chunk size LCr from workspace budget (constant per run) ----
    const long base = (long)NB*PT + 2L*NB*ATOT + 2L*NB*NCLS;
    int LCr = 4;
    if (ws_size >= (size_t)(base + 16L*1572864) * 4) LCr = 16;
    else if (ws_size >= (size_t)(base + 8L*1572864) * 4) LCr = 8;

    float* ws   = (float*)d_ws;
    float* FWp  = ws;
    float* AINp = FWp  + (long)NB * PT;
    float* DZp  = AINp + (long)NB * ATOT;
    float* LOGIp= DZp  + (long)NB * ATOT;
    float* DLOGp= LOGIp + NB * NCLS;
    float* TAp  = DLOGp + NB * NCLS;
    float* TBp  = TAp + (long)NB * LCr * 131072;

    Params12 ps;
    for (int j = 0; j < 12; ++j) ps.p[j] = (const float*)d_in[j];
    {
        long tot = (long)NB * PT;
        bcast_kernel<<<(int)((tot + 255) / 256), 256, 0, stream>>>(ps, FWp);
    }

    for (int t = 0; t < NT; ++t) {
        // ---- forward convs (train): conv_fwd mapping, UF-blocked loads ----
        conv_fwd_u<3,64,64,32,64,64,1,3><<<4096, 256, 0, stream>>>(
            train_x + (long)t * CHW, (long)NT * CHW, FWp, OFF_W0, OFF_B0, AINp + A1, (long)ATOT);
        conv_fwd_u<32,64,64,64,32,32,2,4><<<2048, 256, 0, stream>>>(
            AINp + A1, (long)ATOT, FWp, OFF_W1, OFF_B1, AINp + A2, (long)ATOT);
        conv_fwd_u<64,32,32,128,16,16,2,4><<<1024, 256, 0, stream>>>(
            AINp + A2, (long)ATOT, FWp, OFF_W2, OFF_B2, AINp + A3, (long)ATOT);
        conv_fwd_u<128,16,16,256,8,8,2,4><<<512, 256, 0, stream>>>(
            AINp + A3, (long)ATOT, FWp, OFF_W3, OFF_B3, AINp + A4, (long)ATOT);
        conv_fwd_u<256,8,8,256,4,4,2,8><<<128, 256, 0, stream>>>(
            AINp + A4, (long)ATOT, FWp, OFF_W4, OFF_B4, AINp + A5, (long)ATOT);

        {
            long waves = (long)NB * NCLS;
            head_fwd<<<(int)((waves * 64 + 255) / 256), 256, 0, stream>>>(
                AINp + A5, (long)ATOT, 0,
                train_gate + (long)t * FEAT, (long)NT * FEAT, 0,
                FWp, LOGIp, (long)NCLS, 0, 1);
        }
        softmax_dlogit<<<NB, 128, 0, stream>>>(LOGIp, train_y, t, DLOGp);
        head_bwd_dz5<<<(NB * FEAT + 255) / 256, 256, 0, stream>>>(
            FWp, DLOGp, AINp, train_gate + (long)t * FEAT, (long)NT * FEAT, DZp);
        {
            long tot = (long)NB * NCLS * FEAT;
            head_update<<<(int)((tot + 255) / 256), 256, 0, stream>>>(
                FWp, DLOGp, AINp, train_gate + (long)t * FEAT, (long)NT * FEAT, loglr);
        }

        // ---- backward chain (r9-exact, proven) ----
        conv_bwd_dx2<256,8,8,256,4,4,2,64><<<8*128, 64, 0, stream>>>(
            DZp, A5, FWp, OFF_W4, AINp, A4, DZp, A4);
        {
            long totw = (long)NB * 256 * 256 * 9;
            conv_bwd_dw<<<(int)((totw + 255) / 256), 256, 0, stream>>>(
                FWp, OFF_W4, DZp, A5, AINp + A4, (long)ATOT, loglr,
                256, 8, 8, 256, 4, 4, 2);
            conv_bwd_db<<<(NB * 256 + 255) / 256, 256, 0, stream>>>(
                FWp, OFF_B4, DZp, A5, loglr, 256, 4, 4);
        }
        conv_bwd_dx2<128,16,16,256,8,8,4,256><<<8*32, 256, 0, stream>>>(
            DZp, A4, FWp, OFF_W3, AINp, A3, DZp, A3);
        conv_bwd_dw2<128,16,16,256,8,8,2><<<8*256*128, 64, 0, stream>>>(
            FWp, OFF_W3, OFF_B3, DZp, A4, AINp + A3, (long)ATOT, loglr);
        conv_bwd_dx2<64,32,32,128,16,16,4,256><<<8*16*4, 256, 0, stream>>>(
            DZp, A3, FWp, OFF_W2, AINp, A2, DZp, A2);
        conv_bwd_dw2<64,32,32,128,16,16,2><<<8*128*64, 64, 0, stream>>>(
            FWp, OFF_W2, OFF_B2, DZp, A3, AINp + A2, (long)ATOT, loglr);
        conv_bwd_dx2<32,64,64,64,32,32,4,256><<<8*8*16, 256, 0, stream>>>(
            DZp, A2, FWp, OFF_W1, AINp, A1, DZp, A1);
        conv_bwd_dw2<32,64,64,64,32,32,2><<<8*64*32, 64, 0, stream>>>(
            FWp, OFF_W1, OFF_B1, DZp, A2, AINp + A1, (long)ATOT, loglr);
        conv_bwd_dw2<3,64,64,32,64,64,1><<<8*32*3, 64, 0, stream>>>(
            FWp, OFF_W0, OFF_B0, DZp, A1, train_x + (long)t * CHW, (long)NT * CHW, loglr);
    }

    // 3) test forward
    if (LCr == 16) {
        conv_fwd2<3,64,64,32,64,64,1, 32,1,3><<<NB*16*16, 256, 0, stream>>>(
            test_x, (long)NL * CHW, CHW,
            FWp, OFF_W0, OFF_B0, TAp, 16L * 131072, 16);
        conv_fwd2<32,64,64,64,32,32,2, 16,1,8><<<NB*16*16, 256, 0, stream>>>(
            TAp, 16L * 131072, 131072,
            FWp, OFF_W1, OFF_B1, TBp, 16L * 65536, 16);
        conv_fwd2<64,32,32,128,16,16,2, 16,1,8><<<NB*16*8, 256, 0, stream>>>(
            TBp, 16L * 65536, 65536,
            FWp, OFF_W2, OFF_B2, TAp, 16L * 32768, 16);
        // L3: per-thread-output with n axis; grid = 8*16*256*64/256 = 8192
        conv_fwd_un<128,16,16,256,8,8,2,4,16><<<8192, 256, 0, stream>>>(
            TAp, 16L * 32768, 32768,
            FWp, OFF_W3, OFF_B3, TBp, 16L * 16384);
        // L4: grid = 8*16*256*16/256 = 2048
        conv_fwd_un<256,8,8,256,4,4,2,8,16><<<2048, 256, 0, stream>>>(
            TBp, 16L * 16384, 16384,
            FWp, OFF_W4, OFF_B4, TAp, 16L * 4096);
        {
            long waves = (long)NB * 16 * NCLS;
            head_fwd<<<(int)((waves * 64 + 255) / 256), 256, 0, stream>>>(
                TAp, 16L * FEAT, FEAT,
                test_gate, (long)NL * FEAT, FEAT,
                FWp, out + 257, (long)NL * NCLS, NCLS, 16);
        }
    } else {
        for (int c = 0; c < NL / LCr; ++c) {
            int l0 = c * LCr;
            conv_fwd2<3,64,64,32,64,64,1, 32,1,3><<<NB*LCr*16, 256, 0, stream>>>(
                test_x + (long)l0 * CHW, (long)NL * CHW, CHW,
                FWp, OFF_W0, OFF_B0, TAp, (long)LCr * 131072, LCr);
            conv_fwd2<32,64,64,64,32,32,2, 16,1,8><<<NB*LCr*16, 256, 0, stream>>>(
                TAp, (long)LCr * 131072, 131072,
                FWp, OFF_W1, OFF_B1, TBp, (long)LCr * 65536, LCr);
            conv_fwd2<64,32,32,128,16,16,2, 16,1,8><<<NB*LCr*8, 256, 0, stream>>>(
                TBp, (long)LCr * 65536, 65536,
                FWp, OFF_W2, OFF_B2, TAp, (long)LCr * 32768, LCr);
            conv_fwd2<128,16,16,256,8,8,2, 8,4,8><<<NB*LCr*8, 256, 0, stream>>>(
                TAp, (long)LCr * 32768, 32768,
                FWp, OFF_W3, OFF_B3, TBp, (long)LCr * 16384, LCr);
            conv_fwd2<256,8,8,256,4,4,2, 4,16,8><<<NB*LCr*4, 256, 0, stream>>>(
                TBp, (long)LCr * 16384, 16384,
                FWp, OFF_W4, OFF_B4, TAp, (long)LCr * 4096, LCr);
            {
                long waves = (long)NB * LCr * NCLS;
                head_fwd<<<(int)((waves * 64 + 255) / 256), 256, 0, stream>>>(
                    TAp, (long)LCr * FEAT, FEAT,
                    test_gate + (long)l0 * FEAT, (long)NL * FEAT, FEAT,
                    FWp, out + 257 + (long)l0 * NCLS, (long)NL * NCLS, NCLS, LCr);
            }
        }
    }
    final_loss_eval<<<(NB * NL + 255) / 256, 256, 0, stream>>>(
        out + 257, test_y, out, 0, NL);
    write_lr<<<1, 1, 0, stream>>>(loglr, out);
}

// Round 12
// 5829.696 us; speedup vs baseline: 1.3793x; 1.3793x over previous
//
#include <hip/hip_runtime.h>

// ---------------- problem constants ----------------
#define NB 8          // meta-batch (tasks)
#define NT 5          // inner steps
#define NL 16         // test examples per task
#define NCLS 100
#define FEAT 4096
#define CHW (3*64*64) // 12288

// per-task fast-weight block offsets (floats)
#define OFF_W0 0
#define OFF_B0 864
#define OFF_W1 896
#define OFF_B1 19328
#define OFF_W2 19392
#define OFF_B2 93120
#define OFF_W3 93248
#define OFF_B3 388160
#define OFF_W4 388416
#define OFF_B4 978240
#define OFF_WO 978496
#define OFF_BO 1388096
#define PT     1388196   // floats per task

// per-task inner activation block offsets (floats)
#define A1 0          // 32*64*64 = 131072
#define A2 131072     // 64*32*32 =  65536
#define A3 196608     // 128*16*16 = 32768
#define A4 229376     // 256*8*8  =  16384
#define A5 245760     // 256*4*4  =   4096
#define ATOT 249856

struct Params12 { const float* p[12]; };

// ---------------- broadcast initial params to per-task fast weights ----------------
__global__ void bcast_kernel(Params12 ps, float* __restrict__ fw) {
    const int offs[13] = {OFF_W0,OFF_B0,OFF_W1,OFF_B1,OFF_W2,OFF_B2,OFF_W3,OFF_B3,
                          OFF_W4,OFF_B4,OFF_WO,OFF_BO,PT};
    long idx = (long)blockIdx.x * blockDim.x + threadIdx.x;
    long total = (long)NB * PT;
    if (idx >= total) return;
    int i = (int)(idx % PT);
    int j = 11;
    while (j > 0 && i < offs[j]) --j;
    fw[idx] = ps.p[j][i - offs[j]];
}

// ---------------- generic direct conv fwd + bias + relu (proven) ----------------
__global__ void conv_fwd(const float* __restrict__ xb, long x_ts, long x_es,
                         const float* __restrict__ fw, int woff, int boff,
                         float* __restrict__ yb, long y_ts,
                         int N, int IC, int IH, int IW, int OC, int OH, int OW, int s)
{
    long idx = (long)blockIdx.x * blockDim.x + threadIdx.x;
    long total = (long)NB * N * OC * OH * OW;
    if (idx >= total) return;
    int ow = (int)(idx % OW); long r = idx / OW;
    int oh = (int)(r % OH); r /= OH;
    int oc = (int)(r % OC); r /= OC;
    int n  = (int)(r % N);  int b = (int)(r / N);

    const float* x = xb + (long)b * x_ts + (long)n * x_es;
    const float* w = fw + (long)b * PT + woff + (long)oc * IC * 9;
    float acc = fw[(long)b * PT + boff + oc];
    int ih0 = oh * s - 1, iw0 = ow * s - 1;
    for (int ic = 0; ic < IC; ++ic) {
        const float* xc = x + (long)ic * IH * IW;
        const float* wc = w + ic * 9;
        #pragma unroll
        for (int kh = 0; kh < 3; ++kh) {
            int ih = ih0 + kh;
            if (ih < 0 || ih >= IH) continue;
            #pragma unroll
            for (int kw = 0; kw < 3; ++kw) {
                int iw = iw0 + kw;
                if (iw < 0 || iw >= IW) continue;
                acc += xc[ih * IW + iw] * wc[kh * 3 + kw];
            }
        }
    }
    yb[(long)b * y_ts + (((long)n * OC + oc) * OH + oh) * OW + ow] = fmaxf(acc, 0.f);
}

// ---------------- train-path conv: conv_fwd mapping + UF-blocked loads (proven r7) ----------------
template<int IC,int IH,int IW,int OC,int OH,int OW,int S,int UF>
__global__ __launch_bounds__(256) void conv_fwd_u(
    const float* __restrict__ xb, long x_ts,
    const float* __restrict__ fw, int woff, int boff,
    float* __restrict__ yb, long y_ts)
{
    constexpr int OHW = OH*OW, IHW = IH*IW;
    long idx = (long)blockIdx.x * 256 + threadIdx.x;
    int pix = (int)(idx % OHW); long r = idx / OHW;
    int oc = (int)(r % OC); int b = (int)(r / OC);
    int oh = pix / OW, ow = pix % OW;
    int ih0 = oh*S - 1, iw0 = ow*S - 1;

    const float* x = xb + (long)b * x_ts;
    const float* w = fw + (long)b * PT + woff + (long)oc * IC * 9;
    float acc = fw[(long)b * PT + boff + oc];

    #pragma unroll 1
    for (int ic0 = 0; ic0 < IC; ic0 += UF) {
        float xv[UF][9];
        #pragma unroll
        for (int u = 0; u < UF; ++u) {
            const float* xc = x + (long)(ic0 + u) * IHW;
            #pragma unroll
            for (int kh = 0; kh < 3; ++kh) {
                int ih = ih0 + kh;
                #pragma unroll
                for (int kw = 0; kw < 3; ++kw) {
                    int iw = iw0 + kw;
                    bool v = ((unsigned)ih < (unsigned)IH) && ((unsigned)iw < (unsigned)IW);
                    xv[u][kh*3+kw] = v ? xc[ih*IW + iw] : 0.f;
                }
            }
        }
        #pragma unroll
        for (int u = 0; u < UF; ++u) {
            const float* wc = w + (ic0 + u) * 9;
            #pragma unroll
            for (int k = 0; k < 9; ++k)
                acc += xv[u][k] * wc[k];
        }
    }
    yb[(long)b * y_ts + (long)oc * OHW + pix] = fmaxf(acc, 0.f);
}

// ---------------- tiled conv fwd (test path, shallow layers) — proven r5 ----------------
template<int IC,int IH,int IW,int OC,int OH,int OW,int S,int TOC,int NSUB,int ICB>
__global__ __launch_bounds__(256) void conv_fwd2(
    const float* __restrict__ xb, long x_ts, long x_es,
    const float* __restrict__ fw, int woff, int boff,
    float* __restrict__ yb, long y_ts, int N)
{
    constexpr int OHW = OH*OW, IHW = IH*IW;
    constexpr int PPB = 256/NSUB;          // pixels per block
    constexpr int TILES = OHW/PPB;         // spatial tiles
    constexpr int OCB = NSUB*TOC;          // ocs per block
    constexpr int NOCG = OC/OCB;
    __shared__ float wlds[ICB*9*OCB];      // [icb][k][ocb]

    int bi = blockIdx.x;
    int tile = bi % TILES;
    int ocg  = (bi / TILES) % NOCG;
    int n    = (bi / (TILES*NOCG)) % N;
    int b    = bi / (TILES*NOCG*N);

    int tid = threadIdx.x;
    int pixl = tid % PPB, sub = tid / PPB;
    int pix = tile * PPB + pixl;
    int oc0 = ocg * OCB + sub * TOC;
    int oh = pix / OW, ow = pix % OW;
    int ih0 = oh*S - 1, iw0 = ow*S - 1;

    const float* xp  = xb + (long)b * x_ts + (long)n * x_es;
    const float* fwp = fw + (long)b * PT + woff;
    const float* bp  = fw + (long)b * PT + boff;

    float acc[TOC];
    #pragma unroll
    for (int t = 0; t < TOC; ++t) acc[t] = bp[oc0 + t];

    #pragma unroll 1
    for (int ic0i = 0; ic0i < IC; ic0i += ICB) {
        __syncthreads();
        for (int i = tid; i < ICB*9*OCB; i += 256) {
            int o = i % OCB; int rem = i / OCB; int k = rem % 9; int icb = rem / 9;
            wlds[i] = fwp[((long)(ocg*OCB + o) * IC + ic0i + icb) * 9 + k];
        }
        __syncthreads();
        #pragma unroll 2
        for (int icb = 0; icb < ICB; ++icb) {
            const float* xc = xp + (long)(ic0i + icb) * IHW;
            float xv[9];
            #pragma unroll
            for (int kh = 0; kh < 3; ++kh)
            #pragma unroll
            for (int kw = 0; kw < 3; ++kw) {
                int ih = ih0 + kh, iw = iw0 + kw;
                bool v = ((unsigned)ih < (unsigned)IH) && ((unsigned)iw < (unsigned)IW);
                xv[kh*3+kw] = v ? xc[ih*IW + iw] : 0.f;
            }
            const float* wl = wlds + icb*9*OCB + sub*TOC;
            #pragma unroll
            for (int k = 0; k < 9; ++k) {
                #pragma unroll
                for (int t = 0; t < TOC; ++t)
                    acc[t] += xv[k] * wl[k*OCB + t];
            }
        }
    }

    float* yp = yb + (long)b * y_ts;
    #pragma unroll
    for (int t = 0; t < TOC; ++t)
        yp[((long)n*OC + oc0 + t) * OHW + pix] = fmaxf(acc[t], 0.f);
}

// ---------------- flattened-n tiled conv fwd (deep test layers) — proven r9 ----------------
template<int IC,int IH,int IW,int OC,int OH,int OW,int S,int TOC,int ICB,int NTOT>
__global__ __launch_bounds__(256) void conv_fwd2b(
    const float* __restrict__ xb, long x_ts, long x_es,
    const float* __restrict__ fw, int woff, int boff,
    float* __restrict__ yb, long y_ts)
{
    constexpr int OHW = OH*OW, IHW = IH*IW;
    constexpr int PSP = NTOT*OHW;          // flattened pixel space
    constexpr int TILES = PSP/256;
    constexpr int OCB = TOC;
    constexpr int NOCG = OC/OCB;
    __shared__ float wlds[ICB*9*OCB];      // [icb][k][ocb]

    int bi = blockIdx.x;
    int tile = bi % TILES;
    int ocg  = (bi / TILES) % NOCG;
    int b    = bi / (TILES*NOCG);

    int tid = threadIdx.x;
    int pixg = tile * 256 + tid;
    int n = pixg / OHW, pix = pixg % OHW;
    int oc0 = ocg * OCB;
    int oh = pix / OW, ow = pix % OW;
    int ih0 = oh*S - 1, iw0 = ow*S - 1;

    const float* xp  = xb + (long)b * x_ts + (long)n * x_es;
    const float* fwp = fw + (long)b * PT + woff;
    const float* bp  = fw + (long)b * PT + boff;

    float acc[TOC];
    #pragma unroll
    for (int t = 0; t < TOC; ++t) acc[t] = bp[oc0 + t];

    #pragma unroll 1
    for (int ic0i = 0; ic0i < IC; ic0i += ICB) {
        __syncthreads();
        for (int i = tid; i < ICB*9*OCB; i += 256) {
            int o = i % OCB; int rem = i / OCB; int k = rem % 9; int icb = rem / 9;
            wlds[i] = fwp[((long)(ocg*OCB + o) * IC + ic0i + icb) * 9 + k];
        }
        __syncthreads();
        #pragma unroll 2
        for (int icb = 0; icb < ICB; ++icb) {
            const float* xc = xp + (long)(ic0i + icb) * IHW;
            float xv[9];
            #pragma unroll
            for (int kh = 0; kh < 3; ++kh)
            #pragma unroll
            for (int kw = 0; kw < 3; ++kw) {
                int ih = ih0 + kh, iw = iw0 + kw;
                bool v = ((unsigned)ih < (unsigned)IH) && ((unsigned)iw < (unsigned)IW);
                xv[kh*3+kw] = v ? xc[ih*IW + iw] : 0.f;
            }
            const float* wl = wlds + icb*9*OCB;
            #pragma unroll
            for (int k = 0; k < 9; ++k) {
                #pragma unroll
                for (int t = 0; t < TOC; ++t)
                    acc[t] += xv[k] * wl[k*OCB + t];
            }
        }
    }

    float* yp = yb + (long)b * y_ts;
    #pragma unroll
    for (int t = 0; t < TOC; ++t)
        yp[((long)n*OC + oc0 + t) * OHW + pix] = fmaxf(acc[t], 0.f);
}

// ---------------- head forward ----------------
__global__ void head_fwd(const float* __restrict__ a5b, long a_ts, long a_es,
                         const float* __restrict__ gb, long g_ts, long g_es,
                         const float* __restrict__ fw,
                         float* __restrict__ ob, long o_ts, long o_es, int N)
{
    int wid = (int)(((long)blockIdx.x * blockDim.x + threadIdx.x) >> 6);
    int lane = threadIdx.x & 63;
    int total = NB * N * NCLS;
    if (wid >= total) return;
    int cls = wid % NCLS; int r = wid / NCLS;
    int n = r % N; int b = r / N;
    const float* a5 = a5b + (long)b * a_ts + (long)n * a_es;
    const float* g  = gb  + (long)b * g_ts + (long)n * g_es;
    const float* W  = fw + (long)b * PT + OFF_WO + (long)cls * FEAT;
    float acc = 0.f;
    for (int m = lane; m < FEAT; m += 64) acc += W[m] * a5[m] * g[m];
    for (int off = 32; off; off >>= 1) acc += __shfl_down(acc, off, 64);
    if (lane == 0)
        ob[(long)b * o_ts + (long)n * o_es + cls] = acc + fw[(long)b * PT + OFF_BO + cls];
}

// ---------------- inner softmax -> dlogit ----------------
__global__ void softmax_dlogit(const float* __restrict__ logi, const int* __restrict__ ty, int t,
                               float* __restrict__ dlog)
{
    __shared__ float red[128];
    int b = blockIdx.x, tid = threadIdx.x;
    const float* lo = logi + b * NCLS;
    float v = (tid < NCLS) ? lo[tid] : -1e30f;
    red[tid] = v; __syncthreads();
    for (int s2 = 64; s2; s2 >>= 1) { if (tid < s2) red[tid] = fmaxf(red[tid], red[tid + s2]); __syncthreads(); }
    float mx = red[0]; __syncthreads();
    float e = (tid < NCLS) ? expf(v - mx) : 0.f;
    red[tid] = e; __syncthreads();
    for (int s2 = 64; s2; s2 >>= 1) { if (tid < s2) red[tid] += red[tid + s2]; __syncthreads(); }
    float sum = red[0];
    if (tid < NCLS) {
        int y = ty[b * NT + t];
        dlog[b * NCLS + tid] = e / sum - (tid == y ? 1.f : 0.f);
    }
}

// ---------------- head backward: dz5 ----------------
__global__ void head_bwd_dz5(const float* __restrict__ fw, const float* __restrict__ dlog,
                             const float* __restrict__ ain, const float* __restrict__ gb, long g_ts,
                             float* __restrict__ dz)
{
    int idx = blockIdx.x * blockDim.x + threadIdx.x;
    if (idx >= NB * FEAT) return;
    int m = idx % FEAT, b = idx / FEAT;
    const float* W = fw + (long)b * PT + OFF_WO;
    float df = 0.f;
    for (int c = 0; c < NCLS; ++c) df += W[(long)c * FEAT + m] * dlog[b * NCLS + c];
    float a = ain[(long)b * ATOT + A5 + m];
    dz[(long)b * ATOT + A5 + m] = (a > 0.f) ? df * gb[(long)b * g_ts + m] : 0.f;
}

// ---------------- head update ----------------
__global__ void head_update(float* __restrict__ fw, const float* __restrict__ dlog,
                            const float* __restrict__ ain, const float* __restrict__ gb, long g_ts,
                            const float* __restrict__ loglr)
{
    long idx = (long)blockIdx.x * blockDim.x + threadIdx.x;
    long total = (long)NB * NCLS * FEAT;
    if (idx >= total) return;
    int m = (int)(idx % FEAT); long r = idx / FEAT;
    int c = (int)(r % NCLS); int b = (int)(r / NCLS);
    float lr = expf(loglr[0]);
    float f = ain[(long)b * ATOT + A5 + m] * gb[(long)b * g_ts + m];
    float dl = dlog[b * NCLS + c];
    fw[(long)b * PT + OFF_WO + (long)c * FEAT + m] -= lr * dl * f;
    if (m == 0) fw[(long)b * PT + OFF_BO + c] -= lr * dl;
}

// ---------------- conv backward dX (stride-2, parity taps, LDS weights) — r9 exact ----------------
template<int IC,int IH,int IW,int OC,int OH,int OW,int ICG,int BLK>
__global__ __launch_bounds__(BLK) void conv_bwd_dx2(
    const float* __restrict__ dzbuf, int dz_off,
    const float* __restrict__ fw, int woff,
    const float* __restrict__ ain, int ain_off,
    float* __restrict__ dzin, int dzin_off)
{
    constexpr int IHW = IH*IW, OHW = OH*OW, NICG = IC/ICG, PB = IHW/BLK;
    __shared__ float wlds[OC*9*ICG];   // [oc][k][g]
    int bi = blockIdx.x;
    int pb  = bi % PB;
    int icg = (bi / PB) % NICG;
    int b   = bi / (PB * NICG);
    int ic0 = icg * ICG;
    const float* fwp = fw + (long)b * PT + woff;
    for (int i = threadIdx.x; i < OC*9*ICG; i += BLK) {
        int g = i % ICG; int rem = i / ICG; int k = rem % 9; int oc = rem / 9;
        wlds[i] = fwp[((long)oc * IC + ic0 + g) * 9 + k];
    }
    __syncthreads();

    int pix = pb * BLK + threadIdx.x;
    int ih = pix / IW, iw = pix % IW;
    int kh0 = (ih + 1) & 1, kw0 = (iw + 1) & 1;
    int ohA = (ih + 1 - kh0) >> 1, owA = (iw + 1 - kw0) >> 1;
    float mhA = (ohA < OH) ? 1.f : 0.f;   float mhB = (kh0 == 0) ? 1.f : 0.f;
    float mwA = (owA < OW) ? 1.f : 0.f;   float mwB = (kw0 == 0) ? 1.f : 0.f;
    int ohB = ohA - 1, owB = owA - 1;
    int ohAc = (ohA < OH) ? ohA : 0;  int owAc = (owA < OW) ? owA : 0;
    int ohBc = (ohB >= 0) ? ohB : 0;  int owBc = (owB >= 0) ? owB : 0;

    int oAA = ohAc*OW + owAc; float mAA = mhA*mwA; int kAA = kh0*3 + kw0;
    int oAB = ohAc*OW + owBc; float mAB = mhA*mwB; int kAB = kh0*3 + kw0 + 2;
    int oBA = ohBc*OW + owAc; float mBA = mhB*mwA; int kBA = (kh0+2)*3 + kw0;
    int oBB = ohBc*OW + owBc; float mBB = mhB*mwB; int kBB = (kh0+2)*3 + kw0 + 2;

    const float* dzp = dzbuf + (long)b * ATOT + dz_off;
    float acc[ICG];
    #pragma unroll
    for (int g = 0; g < ICG; ++g) acc[g] = 0.f;

    for (int oc = 0; oc < OC; ++oc) {
        const float* dzo = dzp + oc * OHW;
        float dAA = dzo[oAA] * mAA;
        float dAB = dzo[oAB] * mAB;
        float dBA = dzo[oBA] * mBA;
        float dBB = dzo[oBB] * mBB;
        const float* w = wlds + oc * 9 * ICG;
        #pragma unroll
        for (int g = 0; g < ICG; ++g)
            acc[g] += dAA * w[kAA*ICG+g] + dAB * w[kAB*ICG+g]
                    + dBA * w[kBA*ICG+g] + dBB * w[kBB*ICG+g];
    }
    #pragma unroll
    for (int g = 0; g < ICG; ++g) {
        long p = (long)b * ATOT + (long)(ic0 + g) * IHW + pix;
        float a = ain[p + ain_off];
        dzin[p + dzin_off] = (a > 0.f) ? acc[g] : 0.f;
    }
}

// ---------------- conv backward dW+db: one wave per (b, oc, ic) ----------------
template<int IC,int IH,int IW,int OC,int OH,int OW,int S>
__global__ __launch_bounds__(64) void conv_bwd_dw2(
    float* __restrict__ fw, int woff, int boff,
    const float* __restrict__ dzbuf, int dz_off,
    const float* __restrict__ xb, long x_ts,
    const float* __restrict__ loglr)
{
    constexpr int OHW = OH*OW;
    int bi = blockIdx.x;
    int ic = bi % IC; int oc = (bi / IC) % OC; int b = bi / (IC * OC);
    int lane = threadIdx.x;
    const float* dzp = dzbuf + (long)b * ATOT + dz_off + (long)oc * OHW;
    const float* xp  = xb + (long)b * x_ts + (long)ic * IH * IW;

    float acc[10];
    #pragma unroll
    for (int k = 0; k < 10; ++k) acc[k] = 0.f;

    for (int pos = lane; pos < OHW; pos += 64) {
        float dzv = dzp[pos];
        int oh = pos / OW, ow = pos % OW;
        int ihb = oh * S - 1, iwb = ow * S - 1;
        acc[9] += dzv;
        #pragma unroll
        for (int kh = 0; kh < 3; ++kh) {
            int ih = ihb + kh;
            bool hv = ((unsigned)ih < (unsigned)IH);
            #pragma unroll
            for (int kw = 0; kw < 3; ++kw) {
                int iw = iwb + kw;
                float xv = (hv && (unsigned)iw < (unsigned)IW) ? xp[ih * IW + iw] : 0.f;
                acc[kh*3+kw] += dzv * xv;
            }
        }
    }
    #pragma unroll
    for (int k = 0; k < 10; ++k)
        for (int off = 32; off; off >>= 1) acc[k] += __shfl_down(acc[k], off, 64);

    if (lane == 0) {
        float lr = expf(loglr[0]);
        float* wp = fw + (long)b * PT + woff + ((long)oc * IC + ic) * 9;
        #pragma unroll
        for (int k = 0; k < 9; ++k) wp[k] -= lr * acc[k];
        if (ic == 0) fw[(long)b * PT + boff + oc] -= lr * acc[9];
    }
}

// ---------------- old dW/db (layer 4: tiny spatial) ----------------
__global__ void conv_bwd_dw(float* __restrict__ fw, int woff,
                            const float* __restrict__ dz, long dz_off,
                            const float* __restrict__ xb, long x_ts,
                            const float* __restrict__ loglr,
                            int IC, int IH, int IW, int OC, int OH, int OW, int s)
{
    long idx = (long)blockIdx.x * blockDim.x + threadIdx.x;
    long total = (long)NB * OC * IC * 9;
    if (idx >= total) return;
    int k = (int)(idx % 9); int kw = k % 3, kh = k / 3;
    long r = idx / 9; int ic = (int)(r % IC); r /= IC;
    int oc = (int)(r % OC); int b = (int)(r / OC);
    const float* dzp = dz + (long)b * ATOT + dz_off + (long)oc * OH * OW;
    const float* x = xb + (long)b * x_ts + (long)ic * IH * IW;
    float acc = 0.f;
    for (int oh = 0; oh < OH; ++oh) {
        int ih = oh * s - 1 + kh;
        if (ih < 0 || ih >= IH) continue;
        for (int ow = 0; ow < OW; ++ow) {
            int iw = ow * s - 1 + kw;
            if (iw < 0 || iw >= IW) continue;
            acc += dzp[oh * OW + ow] * x[ih * IW + iw];
        }
    }
    fw[(long)b * PT + woff + ((long)(oc * IC + ic) * 3 + kh) * 3 + kw] -= expf(loglr[0]) * acc;
}

__global__ void conv_bwd_db(float* __restrict__ fw, int boff,
                            const float* __restrict__ dz, long dz_off,
                            const float* __restrict__ loglr, int OC, int OH, int OW)
{
    int idx = blockIdx.x * blockDim.x + threadIdx.x;
    if (idx >= NB * OC) return;
    int oc = idx % OC, b = idx / OC;
    const float* p = dz + (long)b * ATOT + dz_off + (long)oc * OH * OW;
    float acc = 0.f;
    for (int i = 0; i < OH * OW; ++i) acc += p[i];
    fw[(long)b * PT + boff + oc] -= expf(loglr[0]) * acc;
}

// ---------------- final loss / eval ----------------
__global__ void final_loss_eval(const float* __restrict__ logit_base,
                                const int* __restrict__ test_y,
                                float* __restrict__ out, int l0, int Lc)
{
    int idx = blockIdx.x * blockDim.x + threadIdx.x;
    if (idx >= NB * Lc) return;
    int n = idx % Lc, b = idx / Lc;
    int l = l0 + n;
    const float* lo = logit_base + ((long)b * NL + l) * NCLS;
    float mx = -1e30f; int am = 0;
    for (int c = 0; c < NCLS; ++c) { float v = lo[c]; if (v > mx) { mx = v; am = c; } }
    float se = 0.f;
    for (int c = 0; c < NCLS; ++c) se += expf(lo[c] - mx);
    int y = test_y[b * NL + l];
    out[b * NL + l] = -(lo[y] - mx - logf(se));
    out[129 + b * NL + l] = (am == y) ? 1.f : 0.f;
}

__global__ void write_lr(const float* __restrict__ loglr, float* __restrict__ out)
{
    if (threadIdx.x == 0 && blockIdx.x == 0) out[128] = expf(loglr[0]);
}

// ---------------- host orchestration ----------------
extern "C" void kernel_launch(void* const* d_in, const int* in_sizes, int n_in,
                              void* d_out, int out_size, void* d_ws, size_t ws_size,
                              hipStream_t stream)
{
    const float* loglr      = (const float*)d_in[12];
    const float* train_x    = (const float*)d_in[13];
    const float* test_x     = (const float*)d_in[14];
    const float* train_gate = (const float*)d_in[15];
    const float* test_gate  = (const float*)d_in[16];
    const int*   train_y    = (const int*)d_in[17];
    const int*   test_y     = (const int*)d_in[18];
    float* out = (float*)d_out;

    // ---- choose test-chunk size LCr from workspace budget (constant per run) ----
    const long base = (long)NB*PT + 2L*NB*ATOT + 2L*NB*NCLS;
    int LCr = 4;
    if (ws_size >= (size_t)(base + 16L*1572864) * 4) LCr = 16;
    else if (ws_size >= (size_t)(base + 8L*1572864) * 4) LCr = 8;

    float* ws   = (float*)d_ws;
    float* FWp  = ws;
    float* AINp = FWp  + (long)NB * PT;
    float* DZp  = AINp + (long)NB * ATOT;
    float* LOGIp= DZp  + (long)NB * ATOT;
    float* DLOGp= LOGIp + NB * NCLS;
    float* TAp  = DLOGp + NB * NCLS;
    float* TBp  = TAp + (long)NB * LCr * 131072;

    Params12 ps;
    for (int j = 0; j < 12; ++j) ps.p[j] = (const float*)d_in[j];
    {
        long tot = (long)NB * PT;
        bcast_kernel<<<(int)((tot + 255) / 256), 256, 0, stream>>>(ps, FWp);
    }

    for (int t = 0; t < NT; ++t) {
        // ---- forward convs (train): conv_fwd mapping, UF-blocked loads ----
        conv_fwd_u<3,64,64,32,64,64,1,3><<<4096, 256, 0, stream>>>(
            train_x + (long)t * CHW, (long)NT * CHW, FWp, OFF_W0, OFF_B0, AINp + A1, (long)ATOT);
        conv_fwd_u<32,64,64,64,32,32,2,4><<<2048, 256, 0, stream>>>(
            AINp + A1, (long)ATOT, FWp, OFF_W1, OFF_B1, AINp + A2, (long)ATOT);
        conv_fwd_u<64,32,32,128,16,16,2,4><<<1024, 256, 0, stream>>>(
            AINp + A2, (long)ATOT, FWp, OFF_W2, OFF_B2, AINp + A3, (long)ATOT);
        conv_fwd_u<128,16,16,256,8,8,2,4><<<512, 256, 0, stream>>>(
            AINp + A3, (long)ATOT, FWp, OFF_W3, OFF_B3, AINp + A4, (long)ATOT);
        conv_fwd_u<256,8,8,256,4,4,2,8><<<128, 256, 0, stream>>>(
            AINp + A4, (long)ATOT, FWp, OFF_W4, OFF_B4, AINp + A5, (long)ATOT);

        {
            long waves = (long)NB * NCLS;
            head_fwd<<<(int)((waves * 64 + 255) / 256), 256, 0, stream>>>(
                AINp + A5, (long)ATOT, 0,
                train_gate + (long)t * FEAT, (long)NT * FEAT, 0,
                FWp, LOGIp, (long)NCLS, 0, 1);
        }
        softmax_dlogit<<<NB, 128, 0, stream>>>(LOGIp, train_y, t, DLOGp);
        head_bwd_dz5<<<(NB * FEAT + 255) / 256, 256, 0, stream>>>(
            FWp, DLOGp, AINp, train_gate + (long)t * FEAT, (long)NT * FEAT, DZp);
        {
            long tot = (long)NB * NCLS * FEAT;
            head_update<<<(int)((tot + 255) / 256), 256, 0, stream>>>(
                FWp, DLOGp, AINp, train_gate + (long)t * FEAT, (long)NT * FEAT, loglr);
        }

        // ---- backward chain (r9-exact, proven) ----
        conv_bwd_dx2<256,8,8,256,4,4,2,64><<<8*128, 64, 0, stream>>>(
            DZp, A5, FWp, OFF_W4, AINp, A4, DZp, A4);
        {
            long totw = (long)NB * 256 * 256 * 9;
            conv_bwd_dw<<<(int)((totw + 255) / 256), 256, 0, stream>>>(
                FWp, OFF_W4, DZp, A5, AINp + A4, (long)ATOT, loglr,
                256, 8, 8, 256, 4, 4, 2);
            conv_bwd_db<<<(NB * 256 + 255) / 256, 256, 0, stream>>>(
                FWp, OFF_B4, DZp, A5, loglr, 256, 4, 4);
        }
        conv_bwd_dx2<128,16,16,256,8,8,4,256><<<8*32, 256, 0, stream>>>(
            DZp, A4, FWp, OFF_W3, AINp, A3, DZp, A3);
        conv_bwd_dw2<128,16,16,256,8,8,2><<<8*256*128, 64, 0, stream>>>(
            FWp, OFF_W3, OFF_B3, DZp, A4, AINp + A3, (long)ATOT, loglr);
        conv_bwd_dx2<64,32,32,128,16,16,4,256><<<8*16*4, 256, 0, stream>>>(
            DZp, A3, FWp, OFF_W2, AINp, A2, DZp, A2);
        conv_bwd_dw2<64,32,32,128,16,16,2><<<8*128*64, 64, 0, stream>>>(
            FWp, OFF_W2, OFF_B2, DZp, A3, AINp + A2, (long)ATOT, loglr);
        conv_bwd_dx2<32,64,64,64,32,32,4,256><<<8*8*16, 256, 0, stream>>>(
            DZp, A2, FWp, OFF_W1, AINp, A1, DZp, A1);
        conv_bwd_dw2<32,64,64,64,32,32,2><<<8*64*32, 64, 0, stream>>>(
            FWp, OFF_W1, OFF_B1, DZp, A2, AINp + A1, (long)ATOT, loglr);
        conv_bwd_dw2<3,64,64,32,64,64,1><<<8*32*3, 64, 0, stream>>>(
            FWp, OFF_W0, OFF_B0, DZp, A1, train_x + (long)t * CHW, (long)NT * CHW, loglr);
    }

    // 3) test forward
    if (LCr == 16) {
        conv_fwd2<3,64,64,32,64,64,1, 32,1,3><<<NB*16*16, 256, 0, stream>>>(
            test_x, (long)NL * CHW, CHW,
            FWp, OFF_W0, OFF_B0, TAp, 16L * 131072, 16);
        conv_fwd2<32,64,64,64,32,32,2, 16,1,8><<<NB*16*16, 256, 0, stream>>>(
            TAp, 16L * 131072, 131072,
            FWp, OFF_W1, OFF_B1, TBp, 16L * 65536, 16);
        conv_fwd2<64,32,32,128,16,16,2, 16,1,8><<<NB*16*8, 256, 0, stream>>>(
            TBp, 16L * 65536, 65536,
            FWp, OFF_W2, OFF_B2, TAp, 16L * 32768, 16);
        // L3: flattened-n, TOC=8 -> TILES=4, NOCG=32 -> grid 8*4*32 = 1024
        conv_fwd2b<128,16,16,256,8,8,2, 8,8,16><<<NB*4*32, 256, 0, stream>>>(
            TAp, 16L * 32768, 32768,
            FWp, OFF_W3, OFF_B3, TBp, 16L * 16384);
        // L4: flattened-n, TOC=8 -> TILES=1, NOCG=32 -> grid 8*32 = 256
        conv_fwd2b<256,8,8,256,4,4,2, 8,8,16><<<NB*32, 256, 0, stream>>>(
            TBp, 16L * 16384, 16384,
            FWp, OFF_W4, OFF_B4, TAp, 16L * 4096);
        {
            long waves = (long)NB * 16 * NCLS;
            head_fwd<<<(int)((waves * 64 + 255) / 256), 256, 0, stream>>>(
                TAp, 16L * FEAT, FEAT,
                test_gate, (long)NL * FEAT, FEAT,
                FWp, out + 257, (long)NL * NCLS, NCLS, 16);
        }
    } else {
        for (int c = 0; c < NL / LCr; ++c) {
            int l0 = c * LCr;
            conv_fwd2<3,64,64,32,64,64,1, 32,1,3><<<NB*LCr*16, 256, 0, stream>>>(
                test_x + (long)l0 * CHW, (long)NL * CHW, CHW,
                FWp, OFF_W0, OFF_B0, TAp, (long)LCr * 131072, LCr);
            conv_fwd2<32,64,64,64,32,32,2, 16,1,8><<<NB*LCr*16, 256, 0, stream>>>(
                TAp, (long)LCr * 131072, 131072,
                FWp, OFF_W1, OFF_B1, TBp, (long)LCr * 65536, LCr);
            conv_fwd2<64,32,32,128,16,16,2, 16,1,8><<<NB*LCr*8, 256, 0, stream>>>(
                TBp, (long)LCr * 65536, 65536,
                FWp, OFF_W2, OFF_B2, TAp, (long)LCr * 32768, LCr);
            conv_fwd2<128,16,16,256,8,8,2, 8,4,8><<<NB*LCr*8, 256, 0, stream>>>(
                TAp, (long)LCr * 32768, 32768,
                FWp, OFF_W3, OFF_B3, TBp, (long)LCr * 16384, LCr);
            conv_fwd2<256,8,8,256,4,4,2, 4,16,8><<<NB*LCr*4, 256, 0, stream>>>(
                TBp, (long)LCr * 16384, 16384,
                FWp, OFF_W4, OFF_B4, TAp, (long)LCr * 4096, LCr);
            {
                long waves = (long)NB * LCr * NCLS;
                head_fwd<<<(int)((waves * 64 + 255) / 256), 256, 0, stream>>>(
                    TAp, (long)LCr * FEAT, FEAT,
                    test_gate + (long)l0 * FEAT, (long)NL * FEAT, FEAT,
                    FWp, out + 257 + (long)l0 * NCLS, (long)NL * NCLS, NCLS, LCr);
            }
        }
    }
    final_loss_eval<<<(NB * NL + 255) / 256, 256, 0, stream>>>(
        out + 257, test_y, out, 0, NL);
    write_lr<<<1, 1, 0, stream>>>(loglr, out);
}

// Round 13
// 5487.989 us; speedup vs baseline: 1.4652x; 1.0623x over previous
//
#include <hip/hip_runtime.h>

// ---------------- problem constants ----------------
#define NB 8          // meta-batch (tasks)
#define NT 5          // inner steps
#define NL 16         // test examples per task
#define NCLS 100
#define FEAT 4096
#define CHW (3*64*64) // 12288

// per-task fast-weight block offsets (floats)
#define OFF_W0 0
#define OFF_B0 864
#define OFF_W1 896
#define OFF_B1 19328
#define OFF_W2 19392
#define OFF_B2 93120
#define OFF_W3 93248
#define OFF_B3 388160
#define OFF_W4 388416
#define OFF_B4 978240
#define OFF_WO 978496
#define OFF_BO 1388096
#define PT     1388196   // floats per task

// per-task inner activation block offsets (floats)
#define A1 0          // 32*64*64 = 131072
#define A2 131072     // 64*32*32 =  65536
#define A3 196608     // 128*16*16 = 32768
#define A4 229376     // 256*8*8  =  16384
#define A5 245760     // 256*4*4  =   4096
#define ATOT 249856

struct Params12 { const float* p[12]; };

// ---------------- broadcast initial params to per-task fast weights ----------------
__global__ void bcast_kernel(Params12 ps, float* __restrict__ fw) {
    const int offs[13] = {OFF_W0,OFF_B0,OFF_W1,OFF_B1,OFF_W2,OFF_B2,OFF_W3,OFF_B3,
                          OFF_W4,OFF_B4,OFF_WO,OFF_BO,PT};
    long idx = (long)blockIdx.x * blockDim.x + threadIdx.x;
    long total = (long)NB * PT;
    if (idx >= total) return;
    int i = (int)(idx % PT);
    int j = 11;
    while (j > 0 && i < offs[j]) --j;
    fw[idx] = ps.p[j][i - offs[j]];
}

// ---------------- generic direct conv fwd + bias + relu (proven) ----------------
__global__ void conv_fwd(const float* __restrict__ xb, long x_ts, long x_es,
                         const float* __restrict__ fw, int woff, int boff,
                         float* __restrict__ yb, long y_ts,
                         int N, int IC, int IH, int IW, int OC, int OH, int OW, int s)
{
    long idx = (long)blockIdx.x * blockDim.x + threadIdx.x;
    long total = (long)NB * N * OC * OH * OW;
    if (idx >= total) return;
    int ow = (int)(idx % OW); long r = idx / OW;
    int oh = (int)(r % OH); r /= OH;
    int oc = (int)(r % OC); r /= OC;
    int n  = (int)(r % N);  int b = (int)(r / N);

    const float* x = xb + (long)b * x_ts + (long)n * x_es;
    const float* w = fw + (long)b * PT + woff + (long)oc * IC * 9;
    float acc = fw[(long)b * PT + boff + oc];
    int ih0 = oh * s - 1, iw0 = ow * s - 1;
    for (int ic = 0; ic < IC; ++ic) {
        const float* xc = x + (long)ic * IH * IW;
        const float* wc = w + ic * 9;
        #pragma unroll
        for (int kh = 0; kh < 3; ++kh) {
            int ih = ih0 + kh;
            if (ih < 0 || ih >= IH) continue;
            #pragma unroll
            for (int kw = 0; kw < 3; ++kw) {
                int iw = iw0 + kw;
                if (iw < 0 || iw >= IW) continue;
                acc += xc[ih * IW + iw] * wc[kh * 3 + kw];
            }
        }
    }
    yb[(long)b * y_ts + (((long)n * OC + oc) * OH + oh) * OW + ow] = fmaxf(acc, 0.f);
}

// ---------------- train-path conv: conv_fwd mapping + UF-blocked loads (proven r7) ----------------
// BS = block size; per-thread mapping idx = blockIdx*BS + tid (bit-identical across BS).
template<int IC,int IH,int IW,int OC,int OH,int OW,int S,int UF,int BS>
__global__ __launch_bounds__(BS) void conv_fwd_u(
    const float* __restrict__ xb, long x_ts,
    const float* __restrict__ fw, int woff, int boff,
    float* __restrict__ yb, long y_ts)
{
    constexpr int OHW = OH*OW, IHW = IH*IW;
    long idx = (long)blockIdx.x * BS + threadIdx.x;
    int pix = (int)(idx % OHW); long r = idx / OHW;
    int oc = (int)(r % OC); int b = (int)(r / OC);
    int oh = pix / OW, ow = pix % OW;
    int ih0 = oh*S - 1, iw0 = ow*S - 1;

    const float* x = xb + (long)b * x_ts;
    const float* w = fw + (long)b * PT + woff + (long)oc * IC * 9;
    float acc = fw[(long)b * PT + boff + oc];

    #pragma unroll 1
    for (int ic0 = 0; ic0 < IC; ic0 += UF) {
        float xv[UF][9];
        #pragma unroll
        for (int u = 0; u < UF; ++u) {
            const float* xc = x + (long)(ic0 + u) * IHW;
            #pragma unroll
            for (int kh = 0; kh < 3; ++kh) {
                int ih = ih0 + kh;
                #pragma unroll
                for (int kw = 0; kw < 3; ++kw) {
                    int iw = iw0 + kw;
                    bool v = ((unsigned)ih < (unsigned)IH) && ((unsigned)iw < (unsigned)IW);
                    xv[u][kh*3+kw] = v ? xc[ih*IW + iw] : 0.f;
                }
            }
        }
        #pragma unroll
        for (int u = 0; u < UF; ++u) {
            const float* wc = w + (ic0 + u) * 9;
            #pragma unroll
            for (int k = 0; k < 9; ++k)
                acc += xv[u][k] * wc[k];
        }
    }
    yb[(long)b * y_ts + (long)oc * OHW + pix] = fmaxf(acc, 0.f);
}

// ---------------- tiled conv fwd (test path, shallow layers) — proven r5 ----------------
template<int IC,int IH,int IW,int OC,int OH,int OW,int S,int TOC,int NSUB,int ICB>
__global__ __launch_bounds__(256) void conv_fwd2(
    const float* __restrict__ xb, long x_ts, long x_es,
    const float* __restrict__ fw, int woff, int boff,
    float* __restrict__ yb, long y_ts, int N)
{
    constexpr int OHW = OH*OW, IHW = IH*IW;
    constexpr int PPB = 256/NSUB;          // pixels per block
    constexpr int TILES = OHW/PPB;         // spatial tiles
    constexpr int OCB = NSUB*TOC;          // ocs per block
    constexpr int NOCG = OC/OCB;
    __shared__ float wlds[ICB*9*OCB];      // [icb][k][ocb]

    int bi = blockIdx.x;
    int tile = bi % TILES;
    int ocg  = (bi / TILES) % NOCG;
    int n    = (bi / (TILES*NOCG)) % N;
    int b    = bi / (TILES*NOCG*N);

    int tid = threadIdx.x;
    int pixl = tid % PPB, sub = tid / PPB;
    int pix = tile * PPB + pixl;
    int oc0 = ocg * OCB + sub * TOC;
    int oh = pix / OW, ow = pix % OW;
    int ih0 = oh*S - 1, iw0 = ow*S - 1;

    const float* xp  = xb + (long)b * x_ts + (long)n * x_es;
    const float* fwp = fw + (long)b * PT + woff;
    const float* bp  = fw + (long)b * PT + boff;

    float acc[TOC];
    #pragma unroll
    for (int t = 0; t < TOC; ++t) acc[t] = bp[oc0 + t];

    #pragma unroll 1
    for (int ic0i = 0; ic0i < IC; ic0i += ICB) {
        __syncthreads();
        for (int i = tid; i < ICB*9*OCB; i += 256) {
            int o = i % OCB; int rem = i / OCB; int k = rem % 9; int icb = rem / 9;
            wlds[i] = fwp[((long)(ocg*OCB + o) * IC + ic0i + icb) * 9 + k];
        }
        __syncthreads();
        #pragma unroll 2
        for (int icb = 0; icb < ICB; ++icb) {
            const float* xc = xp + (long)(ic0i + icb) * IHW;
            float xv[9];
            #pragma unroll
            for (int kh = 0; kh < 3; ++kh)
            #pragma unroll
            for (int kw = 0; kw < 3; ++kw) {
                int ih = ih0 + kh, iw = iw0 + kw;
                bool v = ((unsigned)ih < (unsigned)IH) && ((unsigned)iw < (unsigned)IW);
                xv[kh*3+kw] = v ? xc[ih*IW + iw] : 0.f;
            }
            const float* wl = wlds + icb*9*OCB + sub*TOC;
            #pragma unroll
            for (int k = 0; k < 9; ++k) {
                #pragma unroll
                for (int t = 0; t < TOC; ++t)
                    acc[t] += xv[k] * wl[k*OCB + t];
            }
        }
    }

    float* yp = yb + (long)b * y_ts;
    #pragma unroll
    for (int t = 0; t < TOC; ++t)
        yp[((long)n*OC + oc0 + t) * OHW + pix] = fmaxf(acc[t], 0.f);
}

// ---------------- flattened-n tiled conv fwd (deep test layers) — proven r9 (TOC=16) ----------------
template<int IC,int IH,int IW,int OC,int OH,int OW,int S,int TOC,int ICB,int NTOT>
__global__ __launch_bounds__(256) void conv_fwd2b(
    const float* __restrict__ xb, long x_ts, long x_es,
    const float* __restrict__ fw, int woff, int boff,
    float* __restrict__ yb, long y_ts)
{
    constexpr int OHW = OH*OW, IHW = IH*IW;
    constexpr int PSP = NTOT*OHW;          // flattened pixel space
    constexpr int TILES = PSP/256;
    constexpr int OCB = TOC;
    constexpr int NOCG = OC/OCB;
    __shared__ float wlds[ICB*9*OCB];      // [icb][k][ocb]

    int bi = blockIdx.x;
    int tile = bi % TILES;
    int ocg  = (bi / TILES) % NOCG;
    int b    = bi / (TILES*NOCG);

    int tid = threadIdx.x;
    int pixg = tile * 256 + tid;
    int n = pixg / OHW, pix = pixg % OHW;
    int oc0 = ocg * OCB;
    int oh = pix / OW, ow = pix % OW;
    int ih0 = oh*S - 1, iw0 = ow*S - 1;

    const float* xp  = xb + (long)b * x_ts + (long)n * x_es;
    const float* fwp = fw + (long)b * PT + woff;
    const float* bp  = fw + (long)b * PT + boff;

    float acc[TOC];
    #pragma unroll
    for (int t = 0; t < TOC; ++t) acc[t] = bp[oc0 + t];

    #pragma unroll 1
    for (int ic0i = 0; ic0i < IC; ic0i += ICB) {
        __syncthreads();
        for (int i = tid; i < ICB*9*OCB; i += 256) {
            int o = i % OCB; int rem = i / OCB; int k = rem % 9; int icb = rem / 9;
            wlds[i] = fwp[((long)(ocg*OCB + o) * IC + ic0i + icb) * 9 + k];
        }
        __syncthreads();
        #pragma unroll 2
        for (int icb = 0; icb < ICB; ++icb) {
            const float* xc = xp + (long)(ic0i + icb) * IHW;
            float xv[9];
            #pragma unroll
            for (int kh = 0; kh < 3; ++kh)
            #pragma unroll
            for (int kw = 0; kw < 3; ++kw) {
                int ih = ih0 + kh, iw = iw0 + kw;
                bool v = ((unsigned)ih < (unsigned)IH) && ((unsigned)iw < (unsigned)IW);
                xv[kh*3+kw] = v ? xc[ih*IW + iw] : 0.f;
            }
            const float* wl = wlds + icb*9*OCB;
            #pragma unroll
            for (int k = 0; k < 9; ++k) {
                #pragma unroll
                for (int t = 0; t < TOC; ++t)
                    acc[t] += xv[k] * wl[k*OCB + t];
            }
        }
    }

    float* yp = yb + (long)b * y_ts;
    #pragma unroll
    for (int t = 0; t < TOC; ++t)
        yp[((long)n*OC + oc0 + t) * OHW + pix] = fmaxf(acc[t], 0.f);
}

// ---------------- head forward ----------------
__global__ void head_fwd(const float* __restrict__ a5b, long a_ts, long a_es,
                         const float* __restrict__ gb, long g_ts, long g_es,
                         const float* __restrict__ fw,
                         float* __restrict__ ob, long o_ts, long o_es, int N)
{
    int wid = (int)(((long)blockIdx.x * blockDim.x + threadIdx.x) >> 6);
    int lane = threadIdx.x & 63;
    int total = NB * N * NCLS;
    if (wid >= total) return;
    int cls = wid % NCLS; int r = wid / NCLS;
    int n = r % N; int b = r / N;
    const float* a5 = a5b + (long)b * a_ts + (long)n * a_es;
    const float* g  = gb  + (long)b * g_ts + (long)n * g_es;
    const float* W  = fw + (long)b * PT + OFF_WO + (long)cls * FEAT;
    float acc = 0.f;
    for (int m = lane; m < FEAT; m += 64) acc += W[m] * a5[m] * g[m];
    for (int off = 32; off; off >>= 1) acc += __shfl_down(acc, off, 64);
    if (lane == 0)
        ob[(long)b * o_ts + (long)n * o_es + cls] = acc + fw[(long)b * PT + OFF_BO + cls];
}

// ---------------- inner softmax -> dlogit ----------------
__global__ void softmax_dlogit(const float* __restrict__ logi, const int* __restrict__ ty, int t,
                               float* __restrict__ dlog)
{
    __shared__ float red[128];
    int b = blockIdx.x, tid = threadIdx.x;
    const float* lo = logi + b * NCLS;
    float v = (tid < NCLS) ? lo[tid] : -1e30f;
    red[tid] = v; __syncthreads();
    for (int s2 = 64; s2; s2 >>= 1) { if (tid < s2) red[tid] = fmaxf(red[tid], red[tid + s2]); __syncthreads(); }
    float mx = red[0]; __syncthreads();
    float e = (tid < NCLS) ? expf(v - mx) : 0.f;
    red[tid] = e; __syncthreads();
    for (int s2 = 64; s2; s2 >>= 1) { if (tid < s2) red[tid] += red[tid + s2]; __syncthreads(); }
    float sum = red[0];
    if (tid < NCLS) {
        int y = ty[b * NT + t];
        dlog[b * NCLS + tid] = e / sum - (tid == y ? 1.f : 0.f);
    }
}

// ---------------- head backward: dz5 ----------------
__global__ void head_bwd_dz5(const float* __restrict__ fw, const float* __restrict__ dlog,
                             const float* __restrict__ ain, const float* __restrict__ gb, long g_ts,
                             float* __restrict__ dz)
{
    int idx = blockIdx.x * blockDim.x + threadIdx.x;
    if (idx >= NB * FEAT) return;
    int m = idx % FEAT, b = idx / FEAT;
    const float* W = fw + (long)b * PT + OFF_WO;
    float df = 0.f;
    for (int c = 0; c < NCLS; ++c) df += W[(long)c * FEAT + m] * dlog[b * NCLS + c];
    float a = ain[(long)b * ATOT + A5 + m];
    dz[(long)b * ATOT + A5 + m] = (a > 0.f) ? df * gb[(long)b * g_ts + m] : 0.f;
}

// ---------------- head update ----------------
__global__ void head_update(float* __restrict__ fw, const float* __restrict__ dlog,
                            const float* __restrict__ ain, const float* __restrict__ gb, long g_ts,
                            const float* __restrict__ loglr)
{
    long idx = (long)blockIdx.x * blockDim.x + threadIdx.x;
    long total = (long)NB * NCLS * FEAT;
    if (idx >= total) return;
    int m = (int)(idx % FEAT); long r = idx / FEAT;
    int c = (int)(r % NCLS); int b = (int)(r / NCLS);
    float lr = expf(loglr[0]);
    float f = ain[(long)b * ATOT + A5 + m] * gb[(long)b * g_ts + m];
    float dl = dlog[b * NCLS + c];
    fw[(long)b * PT + OFF_WO + (long)c * FEAT + m] -= lr * dl * f;
    if (m == 0) fw[(long)b * PT + OFF_BO + c] -= lr * dl;
}

// ---------------- conv backward dX (stride-2, parity taps, LDS weights) — r9 exact ----------------
template<int IC,int IH,int IW,int OC,int OH,int OW,int ICG,int BLK>
__global__ __launch_bounds__(BLK) void conv_bwd_dx2(
    const float* __restrict__ dzbuf, int dz_off,
    const float* __restrict__ fw, int woff,
    const float* __restrict__ ain, int ain_off,
    float* __restrict__ dzin, int dzin_off)
{
    constexpr int IHW = IH*IW, OHW = OH*OW, NICG = IC/ICG, PB = IHW/BLK;
    __shared__ float wlds[OC*9*ICG];   // [oc][k][g]
    int bi = blockIdx.x;
    int pb  = bi % PB;
    int icg = (bi / PB) % NICG;
    int b   = bi / (PB * NICG);
    int ic0 = icg * ICG;
    const float* fwp = fw + (long)b * PT + woff;
    for (int i = threadIdx.x; i < OC*9*ICG; i += BLK) {
        int g = i % ICG; int rem = i / ICG; int k = rem % 9; int oc = rem / 9;
        wlds[i] = fwp[((long)oc * IC + ic0 + g) * 9 + k];
    }
    __syncthreads();

    int pix = pb * BLK + threadIdx.x;
    int ih = pix / IW, iw = pix % IW;
    int kh0 = (ih + 1) & 1, kw0 = (iw + 1) & 1;
    int ohA = (ih + 1 - kh0) >> 1, owA = (iw + 1 - kw0) >> 1;
    float mhA = (ohA < OH) ? 1.f : 0.f;   float mhB = (kh0 == 0) ? 1.f : 0.f;
    float mwA = (owA < OW) ? 1.f : 0.f;   float mwB = (kw0 == 0) ? 1.f : 0.f;
    int ohB = ohA - 1, owB = owA - 1;
    int ohAc = (ohA < OH) ? ohA : 0;  int owAc = (owA < OW) ? owA : 0;
    int ohBc = (ohB >= 0) ? ohB : 0;  int owBc = (owB >= 0) ? owB : 0;

    int oAA = ohAc*OW + owAc; float mAA = mhA*mwA; int kAA = kh0*3 + kw0;
    int oAB = ohAc*OW + owBc; float mAB = mhA*mwB; int kAB = kh0*3 + kw0 + 2;
    int oBA = ohBc*OW + owAc; float mBA = mhB*mwA; int kBA = (kh0+2)*3 + kw0;
    int oBB = ohBc*OW + owBc; float mBB = mhB*mwB; int kBB = (kh0+2)*3 + kw0 + 2;

    const float* dzp = dzbuf + (long)b * ATOT + dz_off;
    float acc[ICG];
    #pragma unroll
    for (int g = 0; g < ICG; ++g) acc[g] = 0.f;

    for (int oc = 0; oc < OC; ++oc) {
        const float* dzo = dzp + oc * OHW;
        float dAA = dzo[oAA] * mAA;
        float dAB = dzo[oAB] * mAB;
        float dBA = dzo[oBA] * mBA;
        float dBB = dzo[oBB] * mBB;
        const float* w = wlds + oc * 9 * ICG;
        #pragma unroll
        for (int g = 0; g < ICG; ++g)
            acc[g] += dAA * w[kAA*ICG+g] + dAB * w[kAB*ICG+g]
                    + dBA * w[kBA*ICG+g] + dBB * w[kBB*ICG+g];
    }
    #pragma unroll
    for (int g = 0; g < ICG; ++g) {
        long p = (long)b * ATOT + (long)(ic0 + g) * IHW + pix;
        float a = ain[p + ain_off];
        dzin[p + dzin_off] = (a > 0.f) ? acc[g] : 0.f;
    }
}

// ---------------- conv backward dW+db: one wave per (b, oc, ic) ----------------
template<int IC,int IH,int IW,int OC,int OH,int OW,int S>
__global__ __launch_bounds__(64) void conv_bwd_dw2(
    float* __restrict__ fw, int woff, int boff,
    const float* __restrict__ dzbuf, int dz_off,
    const float* __restrict__ xb, long x_ts,
    const float* __restrict__ loglr)
{
    constexpr int OHW = OH*OW;
    int bi = blockIdx.x;
    int ic = bi % IC; int oc = (bi / IC) % OC; int b = bi / (IC * OC);
    int lane = threadIdx.x;
    const float* dzp = dzbuf + (long)b * ATOT + dz_off + (long)oc * OHW;
    const float* xp  = xb + (long)b * x_ts + (long)ic * IH * IW;

    float acc[10];
    #pragma unroll
    for (int k = 0; k < 10; ++k) acc[k] = 0.f;

    for (int pos = lane; pos < OHW; pos += 64) {
        float dzv = dzp[pos];
        int oh = pos / OW, ow = pos % OW;
        int ihb = oh * S - 1, iwb = ow * S - 1;
        acc[9] += dzv;
        #pragma unroll
        for (int kh = 0; kh < 3; ++kh) {
            int ih = ihb + kh;
            bool hv = ((unsigned)ih < (unsigned)IH);
            #pragma unroll
            for (int kw = 0; kw < 3; ++kw) {
                int iw = iwb + kw;
                float xv = (hv && (unsigned)iw < (unsigned)IW) ? xp[ih * IW + iw] : 0.f;
                acc[kh*3+kw] += dzv * xv;
            }
        }
    }
    #pragma unroll
    for (int k = 0; k < 10; ++k)
        for (int off = 32; off; off >>= 1) acc[k] += __shfl_down(acc[k], off, 64);

    if (lane == 0) {
        float lr = expf(loglr[0]);
        float* wp = fw + (long)b * PT + woff + ((long)oc * IC + ic) * 9;
        #pragma unroll
        for (int k = 0; k < 9; ++k) wp[k] -= lr * acc[k];
        if (ic == 0) fw[(long)b * PT + boff + oc] -= lr * acc[9];
    }
}

// ---------------- old dW/db (layer 4: tiny spatial) ----------------
__global__ void conv_bwd_dw(float* __restrict__ fw, int woff,
                            const float* __restrict__ dz, long dz_off,
                            const float* __restrict__ xb, long x_ts,
                            const float* __restrict__ loglr,
                            int IC, int IH, int IW, int OC, int OH, int OW, int s)
{
    long idx = (long)blockIdx.x * blockDim.x + threadIdx.x;
    long total = (long)NB * OC * IC * 9;
    if (idx >= total) return;
    int k = (int)(idx % 9); int kw = k % 3, kh = k / 3;
    long r = idx / 9; int ic = (int)(r % IC); r /= IC;
    int oc = (int)(r % OC); int b = (int)(r / OC);
    const float* dzp = dz + (long)b * ATOT + dz_off + (long)oc * OH * OW;
    const float* x = xb + (long)b * x_ts + (long)ic * IH * IW;
    float acc = 0.f;
    for (int oh = 0; oh < OH; ++oh) {
        int ih = oh * s - 1 + kh;
        if (ih < 0 || ih >= IH) continue;
        for (int ow = 0; ow < OW; ++ow) {
            int iw = ow * s - 1 + kw;
            if (iw < 0 || iw >= IW) continue;
            acc += dzp[oh * OW + ow] * x[ih * IW + iw];
        }
    }
    fw[(long)b * PT + woff + ((long)(oc * IC + ic) * 3 + kh) * 3 + kw] -= expf(loglr[0]) * acc;
}

__global__ void conv_bwd_db(float* __restrict__ fw, int boff,
                            const float* __restrict__ dz, long dz_off,
                            const float* __restrict__ loglr, int OC, int OH, int OW)
{
    int idx = blockIdx.x * blockDim.x + threadIdx.x;
    if (idx >= NB * OC) return;
    int oc = idx % OC, b = idx / OC;
    const float* p = dz + (long)b * ATOT + dz_off + (long)oc * OH * OW;
    float acc = 0.f;
    for (int i = 0; i < OH * OW; ++i) acc += p[i];
    fw[(long)b * PT + boff + oc] -= expf(loglr[0]) * acc;
}

// ---------------- final loss / eval ----------------
__global__ void final_loss_eval(const float* __restrict__ logit_base,
                                const int* __restrict__ test_y,
                                float* __restrict__ out, int l0, int Lc)
{
    int idx = blockIdx.x * blockDim.x + threadIdx.x;
    if (idx >= NB * Lc) return;
    int n = idx % Lc, b = idx / Lc;
    int l = l0 + n;
    const float* lo = logit_base + ((long)b * NL + l) * NCLS;
    float mx = -1e30f; int am = 0;
    for (int c = 0; c < NCLS; ++c) { float v = lo[c]; if (v > mx) { mx = v; am = c; } }
    float se = 0.f;
    for (int c = 0; c < NCLS; ++c) se += expf(lo[c] - mx);
    int y = test_y[b * NL + l];
    out[b * NL + l] = -(lo[y] - mx - logf(se));
    out[129 + b * NL + l] = (am == y) ? 1.f : 0.f;
}

__global__ void write_lr(const float* __restrict__ loglr, float* __restrict__ out)
{
    if (threadIdx.x == 0 && blockIdx.x == 0) out[128] = expf(loglr[0]);
}

// ---------------- host orchestration ----------------
extern "C" void kernel_launch(void* const* d_in, const int* in_sizes, int n_in,
                              void* d_out, int out_size, void* d_ws, size_t ws_size,
                              hipStream_t stream)
{
    const float* loglr      = (const float*)d_in[12];
    const float* train_x    = (const float*)d_in[13];
    const float* test_x     = (const float*)d_in[14];
    const float* train_gate = (const float*)d_in[15];
    const float* test_gate  = (const float*)d_in[16];
    const int*   train_y    = (const int*)d_in[17];
    const int*   test_y     = (const int*)d_in[18];
    float* out = (float*)d_out;

    // ---- choose test-chunk size LCr from workspace budget (constant per run) ----
    const long base = (long)NB*PT + 2L*NB*ATOT + 2L*NB*NCLS;
    int LCr = 4;
    if (ws_size >= (size_t)(base + 16L*1572864) * 4) LCr = 16;
    else if (ws_size >= (size_t)(base + 8L*1572864) * 4) LCr = 8;

    float* ws   = (float*)d_ws;
    float* FWp  = ws;
    float* AINp = FWp  + (long)NB * PT;
    float* DZp  = AINp + (long)NB * ATOT;
    float* LOGIp= DZp  + (long)NB * ATOT;
    float* DLOGp= LOGIp + NB * NCLS;
    float* TAp  = DLOGp + NB * NCLS;
    float* TBp  = TAp + (long)NB * LCr * 131072;

    Params12 ps;
    for (int j = 0; j < 12; ++j) ps.p[j] = (const float*)d_in[j];
    {
        long tot = (long)NB * PT;
        bcast_kernel<<<(int)((tot + 255) / 256), 256, 0, stream>>>(ps, FWp);
    }

    for (int t = 0; t < NT; ++t) {
        // ---- forward convs (train): conv_fwd mapping, UF-blocked loads ----
        conv_fwd_u<3,64,64,32,64,64,1,3,256><<<4096, 256, 0, stream>>>(
            train_x + (long)t * CHW, (long)NT * CHW, FWp, OFF_W0, OFF_B0, AINp + A1, (long)ATOT);
        conv_fwd_u<32,64,64,64,32,32,2,4,256><<<2048, 256, 0, stream>>>(
            AINp + A1, (long)ATOT, FWp, OFF_W1, OFF_B1, AINp + A2, (long)ATOT);
        conv_fwd_u<64,32,32,128,16,16,2,4,256><<<1024, 256, 0, stream>>>(
            AINp + A2, (long)ATOT, FWp, OFF_W2, OFF_B2, AINp + A3, (long)ATOT);
        // L3/L4: same thread range, 64-thread blocks -> spread across all CUs
        conv_fwd_u<128,16,16,256,8,8,2,4,64><<<2048, 64, 0, stream>>>(
            AINp + A3, (long)ATOT, FWp, OFF_W3, OFF_B3, AINp + A4, (long)ATOT);
        conv_fwd_u<256,8,8,256,4,4,2,8,64><<<512, 64, 0, stream>>>(
            AINp + A4, (long)ATOT, FWp, OFF_W4, OFF_B4, AINp + A5, (long)ATOT);

        {
            long waves = (long)NB * NCLS;
            head_fwd<<<(int)((waves * 64 + 255) / 256), 256, 0, stream>>>(
                AINp + A5, (long)ATOT, 0,
                train_gate + (long)t * FEAT, (long)NT * FEAT, 0,
                FWp, LOGIp, (long)NCLS, 0, 1);
        }
        softmax_dlogit<<<NB, 128, 0, stream>>>(LOGIp, train_y, t, DLOGp);
        head_bwd_dz5<<<(NB * FEAT + 255) / 256, 256, 0, stream>>>(
            FWp, DLOGp, AINp, train_gate + (long)t * FEAT, (long)NT * FEAT, DZp);
        {
            long tot = (long)NB * NCLS * FEAT;
            head_update<<<(int)((tot + 255) / 256), 256, 0, stream>>>(
                FWp, DLOGp, AINp, train_gate + (long)t * FEAT, (long)NT * FEAT, loglr);
        }

        // ---- backward chain (r9-exact, proven) ----
        conv_bwd_dx2<256,8,8,256,4,4,2,64><<<8*128, 64, 0, stream>>>(
            DZp, A5, FWp, OFF_W4, AINp, A4, DZp, A4);
        {
            long totw = (long)NB * 256 * 256 * 9;
            conv_bwd_dw<<<(int)((totw + 255) / 256), 256, 0, stream>>>(
                FWp, OFF_W4, DZp, A5, AINp + A4, (long)ATOT, loglr,
                256, 8, 8, 256, 4, 4, 2);
            conv_bwd_db<<<(NB * 256 + 255) / 256, 256, 0, stream>>>(
                FWp, OFF_B4, DZp, A5, loglr, 256, 4, 4);
        }
        conv_bwd_dx2<128,16,16,256,8,8,4,256><<<8*32, 256, 0, stream>>>(
            DZp, A4, FWp, OFF_W3, AINp, A3, DZp, A3);
        conv_bwd_dw2<128,16,16,256,8,8,2><<<8*256*128, 64, 0, stream>>>(
            FWp, OFF_W3, OFF_B3, DZp, A4, AINp + A3, (long)ATOT, loglr);
        conv_bwd_dx2<64,32,32,128,16,16,4,256><<<8*16*4, 256, 0, stream>>>(
            DZp, A3, FWp, OFF_W2, AINp, A2, DZp, A2);
        conv_bwd_dw2<64,32,32,128,16,16,2><<<8*128*64, 64, 0, stream>>>(
            FWp, OFF_W2, OFF_B2, DZp, A3, AINp + A2, (long)ATOT, loglr);
        conv_bwd_dx2<32,64,64,64,32,32,4,256><<<8*8*16, 256, 0, stream>>>(
            DZp, A2, FWp, OFF_W1, AINp, A1, DZp, A1);
        conv_bwd_dw2<32,64,64,64,32,32,2><<<8*64*32, 64, 0, stream>>>(
            FWp, OFF_W1, OFF_B1, DZp, A2, AINp + A1, (long)ATOT, loglr);
        conv_bwd_dw2<3,64,64,32,64,64,1><<<8*32*3, 64, 0, stream>>>(
            FWp, OFF_W0, OFF_B0, DZp, A1, train_x + (long)t * CHW, (long)NT * CHW, loglr);
    }

    // 3) test forward
    if (LCr == 16) {
        conv_fwd2<3,64,64,32,64,64,1, 32,1,3><<<NB*16*16, 256, 0, stream>>>(
            test_x, (long)NL * CHW, CHW,
            FWp, OFF_W0, OFF_B0, TAp, 16L * 131072, 16);
        conv_fwd2<32,64,64,64,32,32,2, 16,1,8><<<NB*16*16, 256, 0, stream>>>(
            TAp, 16L * 131072, 131072,
            FWp, OFF_W1, OFF_B1, TBp, 16L * 65536, 16);
        conv_fwd2<64,32,32,128,16,16,2, 16,1,8><<<NB*16*8, 256, 0, stream>>>(
            TBp, 16L * 65536, 65536,
            FWp, OFF_W2, OFF_B2, TAp, 16L * 32768, 16);
        // L3: flattened-n, TOC=16 (r9 proven) -> grid 8*4*16 = 512
        conv_fwd2b<128,16,16,256,8,8,2, 16,8,16><<<NB*4*16, 256, 0, stream>>>(
            TAp, 16L * 32768, 32768,
            FWp, OFF_W3, OFF_B3, TBp, 16L * 16384);
        // L4: flattened-n, TOC=16 (r9 proven) -> grid 8*16 = 128
        conv_fwd2b<256,8,8,256,4,4,2, 16,8,16><<<NB*16, 256, 0, stream>>>(
            TBp, 16L * 16384, 16384,
            FWp, OFF_W4, OFF_B4, TAp, 16L * 4096);
        {
            long waves = (long)NB * 16 * NCLS;
            head_fwd<<<(int)((waves * 64 + 255) / 256), 256, 0, stream>>>(
                TAp, 16L * FEAT, FEAT,
                test_gate, (long)NL * FEAT, FEAT,
                FWp, out + 257, (long)NL * NCLS, NCLS, 16);
        }
    } else {
        for (int c = 0; c < NL / LCr; ++c) {
            int l0 = c * LCr;
            conv_fwd2<3,64,64,32,64,64,1, 32,1,3><<<NB*LCr*16, 256, 0, stream>>>(
                test_x + (long)l0 * CHW, (long)NL * CHW, CHW,
                FWp, OFF_W0, OFF_B0, TAp, (long)LCr * 131072, LCr);
            conv_fwd2<32,64,64,64,32,32,2, 16,1,8><<<NB*LCr*16, 256, 0, stream>>>(
                TAp, (long)LCr * 131072, 131072,
                FWp, OFF_W1, OFF_B1, TBp, (long)LCr * 65536, LCr);
            conv_fwd2<64,32,32,128,16,16,2, 16,1,8><<<NB*LCr*8, 256, 0, stream>>>(
                TBp, (long)LCr * 65536, 65536,
                FWp, OFF_W2, OFF_B2, TAp, (long)LCr * 32768, LCr);
            conv_fwd2<128,16,16,256,8,8,2, 8,4,8><<<NB*LCr*8, 256, 0, stream>>>(
                TAp, (long)LCr * 32768, 32768,
                FWp, OFF_W3, OFF_B3, TBp, (long)LCr * 16384, LCr);
            conv_fwd2<256,8,8,256,4,4,2, 4,16,8><<<NB*LCr*4, 256, 0, stream>>>(
                TBp, (long)LCr * 16384, 16384,
                FWp, OFF_W4, OFF_B4, TAp, (long)LCr * 4096, LCr);
            {
                long waves = (long)NB * LCr * NCLS;
                head_fwd<<<(int)((waves * 64 + 255) / 256), 256, 0, stream>>>(
                    TAp, (long)LCr * FEAT, FEAT,
                    test_gate + (long)l0 * FEAT, (long)NL * FEAT, FEAT,
                    FWp, out + 257 + (long)l0 * NCLS, (long)NL * NCLS, NCLS, LCr);
            }
        }
    }
    final_loss_eval<<<(NB * NL + 255) / 256, 256, 0, stream>>>(
        out + 257, test_y, out, 0, NL);
    write_lr<<<1, 1, 0, stream>>>(loglr, out);
}

// Round 15
// 5479.559 us; speedup vs baseline: 1.4674x; 1.0015x over previous
//
#include <hip/hip_runtime.h>

// ---------------- problem constants ----------------
#define NB 8          // meta-batch (tasks)
#define NT 5          // inner steps
#define NL 16         // test examples per task
#define NCLS 100
#define FEAT 4096
#define CHW (3*64*64) // 12288

// per-task fast-weight block offsets (floats)
#define OFF_W0 0
#define OFF_B0 864
#define OFF_W1 896
#define OFF_B1 19328
#define OFF_W2 19392
#define OFF_B2 93120
#define OFF_W3 93248
#define OFF_B3 388160
#define OFF_W4 388416
#define OFF_B4 978240
#define OFF_WO 978496
#define OFF_BO 1388096
#define PT     1388196   // floats per task

// per-task inner activation block offsets (floats)
#define A1 0          // 32*64*64 = 131072
#define A2 131072     // 64*32*32 =  65536
#define A3 196608     // 128*16*16 = 32768
#define A4 229376     // 256*8*8  =  16384
#define A5 245760     // 256*4*4  =   4096
#define ATOT 249856

struct Params12 { const float* p[12]; };

// ---------------- broadcast initial params to per-task fast weights ----------------
__global__ void bcast_kernel(Params12 ps, float* __restrict__ fw) {
    const int offs[13] = {OFF_W0,OFF_B0,OFF_W1,OFF_B1,OFF_W2,OFF_B2,OFF_W3,OFF_B3,
                          OFF_W4,OFF_B4,OFF_WO,OFF_BO,PT};
    long idx = (long)blockIdx.x * blockDim.x + threadIdx.x;
    long total = (long)NB * PT;
    if (idx >= total) return;
    int i = (int)(idx % PT);
    int j = 11;
    while (j > 0 && i < offs[j]) --j;
    fw[idx] = ps.p[j][i - offs[j]];
}

// ---------------- generic direct conv fwd + bias + relu (proven) ----------------
__global__ void conv_fwd(const float* __restrict__ xb, long x_ts, long x_es,
                         const float* __restrict__ fw, int woff, int boff,
                         float* __restrict__ yb, long y_ts,
                         int N, int IC, int IH, int IW, int OC, int OH, int OW, int s)
{
    long idx = (long)blockIdx.x * blockDim.x + threadIdx.x;
    long total = (long)NB * N * OC * OH * OW;
    if (idx >= total) return;
    int ow = (int)(idx % OW); long r = idx / OW;
    int oh = (int)(r % OH); r /= OH;
    int oc = (int)(r % OC); r /= OC;
    int n  = (int)(r % N);  int b = (int)(r / N);

    const float* x = xb + (long)b * x_ts + (long)n * x_es;
    const float* w = fw + (long)b * PT + woff + (long)oc * IC * 9;
    float acc = fw[(long)b * PT + boff + oc];
    int ih0 = oh * s - 1, iw0 = ow * s - 1;
    for (int ic = 0; ic < IC; ++ic) {
        const float* xc = x + (long)ic * IH * IW;
        const float* wc = w + ic * 9;
        #pragma unroll
        for (int kh = 0; kh < 3; ++kh) {
            int ih = ih0 + kh;
            if (ih < 0 || ih >= IH) continue;
            #pragma unroll
            for (int kw = 0; kw < 3; ++kw) {
                int iw = iw0 + kw;
                if (iw < 0 || iw >= IW) continue;
                acc += xc[ih * IW + iw] * wc[kh * 3 + kw];
            }
        }
    }
    yb[(long)b * y_ts + (((long)n * OC + oc) * OH + oh) * OW + ow] = fmaxf(acc, 0.f);
}

// ---------------- train-path conv: conv_fwd mapping + UF-blocked loads (proven r7) ----------------
// BS = block size; per-thread mapping idx = blockIdx*BS + tid (bit-identical across BS).
template<int IC,int IH,int IW,int OC,int OH,int OW,int S,int UF,int BS>
__global__ __launch_bounds__(BS) void conv_fwd_u(
    const float* __restrict__ xb, long x_ts,
    const float* __restrict__ fw, int woff, int boff,
    float* __restrict__ yb, long y_ts)
{
    constexpr int OHW = OH*OW, IHW = IH*IW;
    long idx = (long)blockIdx.x * BS + threadIdx.x;
    int pix = (int)(idx % OHW); long r = idx / OHW;
    int oc = (int)(r % OC); int b = (int)(r / OC);
    int oh = pix / OW, ow = pix % OW;
    int ih0 = oh*S - 1, iw0 = ow*S - 1;

    const float* x = xb + (long)b * x_ts;
    const float* w = fw + (long)b * PT + woff + (long)oc * IC * 9;
    float acc = fw[(long)b * PT + boff + oc];

    #pragma unroll 1
    for (int ic0 = 0; ic0 < IC; ic0 += UF) {
        float xv[UF][9];
        #pragma unroll
        for (int u = 0; u < UF; ++u) {
            const float* xc = x + (long)(ic0 + u) * IHW;
            #pragma unroll
            for (int kh = 0; kh < 3; ++kh) {
                int ih = ih0 + kh;
                #pragma unroll
                for (int kw = 0; kw < 3; ++kw) {
                    int iw = iw0 + kw;
                    bool v = ((unsigned)ih < (unsigned)IH) && ((unsigned)iw < (unsigned)IW);
                    xv[u][kh*3+kw] = v ? xc[ih*IW + iw] : 0.f;
                }
            }
        }
        #pragma unroll
        for (int u = 0; u < UF; ++u) {
            const float* wc = w + (ic0 + u) * 9;
            #pragma unroll
            for (int k = 0; k < 9; ++k)
                acc += xv[u][k] * wc[k];
        }
    }
    yb[(long)b * y_ts + (long)oc * OHW + pix] = fmaxf(acc, 0.f);
}

// ---------------- tiled conv fwd (test path, shallow layers) — proven r5 ----------------
template<int IC,int IH,int IW,int OC,int OH,int OW,int S,int TOC,int NSUB,int ICB>
__global__ __launch_bounds__(256) void conv_fwd2(
    const float* __restrict__ xb, long x_ts, long x_es,
    const float* __restrict__ fw, int woff, int boff,
    float* __restrict__ yb, long y_ts, int N)
{
    constexpr int OHW = OH*OW, IHW = IH*IW;
    constexpr int PPB = 256/NSUB;          // pixels per block
    constexpr int TILES = OHW/PPB;         // spatial tiles
    constexpr int OCB = NSUB*TOC;          // ocs per block
    constexpr int NOCG = OC/OCB;
    __shared__ float wlds[ICB*9*OCB];      // [icb][k][ocb]

    int bi = blockIdx.x;
    int tile = bi % TILES;
    int ocg  = (bi / TILES) % NOCG;
    int n    = (bi / (TILES*NOCG)) % N;
    int b    = bi / (TILES*NOCG*N);

    int tid = threadIdx.x;
    int pixl = tid % PPB, sub = tid / PPB;
    int pix = tile * PPB + pixl;
    int oc0 = ocg * OCB + sub * TOC;
    int oh = pix / OW, ow = pix % OW;
    int ih0 = oh*S - 1, iw0 = ow*S - 1;

    const float* xp  = xb + (long)b * x_ts + (long)n * x_es;
    const float* fwp = fw + (long)b * PT + woff;
    const float* bp  = fw + (long)b * PT + boff;

    float acc[TOC];
    #pragma unroll
    for (int t = 0; t < TOC; ++t) acc[t] = bp[oc0 + t];

    #pragma unroll 1
    for (int ic0i = 0; ic0i < IC; ic0i += ICB) {
        __syncthreads();
        for (int i = tid; i < ICB*9*OCB; i += 256) {
            int o = i % OCB; int rem = i / OCB; int k = rem % 9; int icb = rem / 9;
            wlds[i] = fwp[((long)(ocg*OCB + o) * IC + ic0i + icb) * 9 + k];
        }
        __syncthreads();
        #pragma unroll 2
        for (int icb = 0; icb < ICB; ++icb) {
            const float* xc = xp + (long)(ic0i + icb) * IHW;
            float xv[9];
            #pragma unroll
            for (int kh = 0; kh < 3; ++kh)
            #pragma unroll
            for (int kw = 0; kw < 3; ++kw) {
                int ih = ih0 + kh, iw = iw0 + kw;
                bool v = ((unsigned)ih < (unsigned)IH) && ((unsigned)iw < (unsigned)IW);
                xv[kh*3+kw] = v ? xc[ih*IW + iw] : 0.f;
            }
            const float* wl = wlds + icb*9*OCB + sub*TOC;
            #pragma unroll
            for (int k = 0; k < 9; ++k) {
                #pragma unroll
                for (int t = 0; t < TOC; ++t)
                    acc[t] += xv[k] * wl[k*OCB + t];
            }
        }
    }

    float* yp = yb + (long)b * y_ts;
    #pragma unroll
    for (int t = 0; t < TOC; ++t)
        yp[((long)n*OC + oc0 + t) * OHW + pix] = fmaxf(acc[t], 0.f);
}

// ---------------- flattened-n tiled conv fwd (deep test layers) — proven r9 (TOC=16, ICB=8) ----------------
template<int IC,int IH,int IW,int OC,int OH,int OW,int S,int TOC,int ICB,int NTOT>
__global__ __launch_bounds__(256) void conv_fwd2b(
    const float* __restrict__ xb, long x_ts, long x_es,
    const float* __restrict__ fw, int woff, int boff,
    float* __restrict__ yb, long y_ts)
{
    constexpr int OHW = OH*OW, IHW = IH*IW;
    constexpr int PSP = NTOT*OHW;          // flattened pixel space
    constexpr int TILES = PSP/256;
    constexpr int OCB = TOC;
    constexpr int NOCG = OC/OCB;
    __shared__ float wlds[ICB*9*OCB];      // [icb][k][ocb]

    int bi = blockIdx.x;
    int tile = bi % TILES;
    int ocg  = (bi / TILES) % NOCG;
    int b    = bi / (TILES*NOCG);

    int tid = threadIdx.x;
    int pixg = tile * 256 + tid;
    int n = pixg / OHW, pix = pixg % OHW;
    int oc0 = ocg * OCB;
    int oh = pix / OW, ow = pix % OW;
    int ih0 = oh*S - 1, iw0 = ow*S - 1;

    const float* xp  = xb + (long)b * x_ts + (long)n * x_es;
    const float* fwp = fw + (long)b * PT + woff;
    const float* bp  = fw + (long)b * PT + boff;

    float acc[TOC];
    #pragma unroll
    for (int t = 0; t < TOC; ++t) acc[t] = bp[oc0 + t];

    #pragma unroll 1
    for (int ic0i = 0; ic0i < IC; ic0i += ICB) {
        __syncthreads();
        for (int i = tid; i < ICB*9*OCB; i += 256) {
            int o = i % OCB; int rem = i / OCB; int k = rem % 9; int icb = rem / 9;
            wlds[i] = fwp[((long)(ocg*OCB + o) * IC + ic0i + icb) * 9 + k];
        }
        __syncthreads();
        #pragma unroll 2
        for (int icb = 0; icb < ICB; ++icb) {
            const float* xc = xp + (long)(ic0i + icb) * IHW;
            float xv[9];
            #pragma unroll
            for (int kh = 0; kh < 3; ++kh)
            #pragma unroll
            for (int kw = 0; kw < 3; ++kw) {
                int ih = ih0 + kh, iw = iw0 + kw;
                bool v = ((unsigned)ih < (unsigned)IH) && ((unsigned)iw < (unsigned)IW);
                xv[kh*3+kw] = v ? xc[ih*IW + iw] : 0.f;
            }
            const float* wl = wlds + icb*9*OCB;
            #pragma unroll
            for (int k = 0; k < 9; ++k) {
                #pragma unroll
                for (int t = 0; t < TOC; ++t)
                    acc[t] += xv[k] * wl[k*OCB + t];
            }
        }
    }

    float* yp = yb + (long)b * y_ts;
    #pragma unroll
    for (int t = 0; t < TOC; ++t)
        yp[((long)n*OC + oc0 + t) * OHW + pix] = fmaxf(acc[t], 0.f);
}

// ---------------- head forward ----------------
__global__ void head_fwd(const float* __restrict__ a5b, long a_ts, long a_es,
                         const float* __restrict__ gb, long g_ts, long g_es,
                         const float* __restrict__ fw,
                         float* __restrict__ ob, long o_ts, long o_es, int N)
{
    int wid = (int)(((long)blockIdx.x * blockDim.x + threadIdx.x) >> 6);
    int lane = threadIdx.x & 63;
    int total = NB * N * NCLS;
    if (wid >= total) return;
    int cls = wid % NCLS; int r = wid / NCLS;
    int n = r % N; int b = r / N;
    const float* a5 = a5b + (long)b * a_ts + (long)n * a_es;
    const float* g  = gb  + (long)b * g_ts + (long)n * g_es;
    const float* W  = fw + (long)b * PT + OFF_WO + (long)cls * FEAT;
    float acc = 0.f;
    for (int m = lane; m < FEAT; m += 64) acc += W[m] * a5[m] * g[m];
    for (int off = 32; off; off >>= 1) acc += __shfl_down(acc, off, 64);
    if (lane == 0)
        ob[(long)b * o_ts + (long)n * o_es + cls] = acc + fw[(long)b * PT + OFF_BO + cls];
}

// ---------------- inner softmax -> dlogit ----------------
__global__ void softmax_dlogit(const float* __restrict__ logi, const int* __restrict__ ty, int t,
                               float* __restrict__ dlog)
{
    __shared__ float red[128];
    int b = blockIdx.x, tid = threadIdx.x;
    const float* lo = logi + b * NCLS;
    float v = (tid < NCLS) ? lo[tid] : -1e30f;
    red[tid] = v; __syncthreads();
    for (int s2 = 64; s2; s2 >>= 1) { if (tid < s2) red[tid] = fmaxf(red[tid], red[tid + s2]); __syncthreads(); }
    float mx = red[0]; __syncthreads();
    float e = (tid < NCLS) ? expf(v - mx) : 0.f;
    red[tid] = e; __syncthreads();
    for (int s2 = 64; s2; s2 >>= 1) { if (tid < s2) red[tid] += red[tid + s2]; __syncthreads(); }
    float sum = red[0];
    if (tid < NCLS) {
        int y = ty[b * NT + t];
        dlog[b * NCLS + tid] = e / sum - (tid == y ? 1.f : 0.f);
    }
}

// ---------------- head backward: dz5 ----------------
__global__ void head_bwd_dz5(const float* __restrict__ fw, const float* __restrict__ dlog,
                             const float* __restrict__ ain, const float* __restrict__ gb, long g_ts,
                             float* __restrict__ dz)
{
    int idx = blockIdx.x * blockDim.x + threadIdx.x;
    if (idx >= NB * FEAT) return;
    int m = idx % FEAT, b = idx / FEAT;
    const float* W = fw + (long)b * PT + OFF_WO;
    float df = 0.f;
    for (int c = 0; c < NCLS; ++c) df += W[(long)c * FEAT + m] * dlog[b * NCLS + c];
    float a = ain[(long)b * ATOT + A5 + m];
    dz[(long)b * ATOT + A5 + m] = (a > 0.f) ? df * gb[(long)b * g_ts + m] : 0.f;
}

// ---------------- head update ----------------
__global__ void head_update(float* __restrict__ fw, const float* __restrict__ dlog,
                            const float* __restrict__ ain, const float* __restrict__ gb, long g_ts,
                            const float* __restrict__ loglr)
{
    long idx = (long)blockIdx.x * blockDim.x + threadIdx.x;
    long total = (long)NB * NCLS * FEAT;
    if (idx >= total) return;
    int m = (int)(idx % FEAT); long r = idx / FEAT;
    int c = (int)(r % NCLS); int b = (int)(r / NCLS);
    float lr = expf(loglr[0]);
    float f = ain[(long)b * ATOT + A5 + m] * gb[(long)b * g_ts + m];
    float dl = dlog[b * NCLS + c];
    fw[(long)b * PT + OFF_WO + (long)c * FEAT + m] -= lr * dl * f;
    if (m == 0) fw[(long)b * PT + OFF_BO + c] -= lr * dl;
}

// ---------------- conv backward dX (stride-2, parity taps, LDS weights) — r9 exact, FROZEN ----------------
template<int IC,int IH,int IW,int OC,int OH,int OW,int ICG,int BLK>
__global__ __launch_bounds__(BLK) void conv_bwd_dx2(
    const float* __restrict__ dzbuf, int dz_off,
    const float* __restrict__ fw, int woff,
    const float* __restrict__ ain, int ain_off,
    float* __restrict__ dzin, int dzin_off)
{
    constexpr int IHW = IH*IW, OHW = OH*OW, NICG = IC/ICG, PB = IHW/BLK;
    __shared__ float wlds[OC*9*ICG];   // [oc][k][g]
    int bi = blockIdx.x;
    int pb  = bi % PB;
    int icg = (bi / PB) % NICG;
    int b   = bi / (PB * NICG);
    int ic0 = icg * ICG;
    const float* fwp = fw + (long)b * PT + woff;
    for (int i = threadIdx.x; i < OC*9*ICG; i += BLK) {
        int g = i % ICG; int rem = i / ICG; int k = rem % 9; int oc = rem / 9;
        wlds[i] = fwp[((long)oc * IC + ic0 + g) * 9 + k];
    }
    __syncthreads();

    int pix = pb * BLK + threadIdx.x;
    int ih = pix / IW, iw = pix % IW;
    int kh0 = (ih + 1) & 1, kw0 = (iw + 1) & 1;
    int ohA = (ih + 1 - kh0) >> 1, owA = (iw + 1 - kw0) >> 1;
    float mhA = (ohA < OH) ? 1.f : 0.f;   float mhB = (kh0 == 0) ? 1.f : 0.f;
    float mwA = (owA < OW) ? 1.f : 0.f;   float mwB = (kw0 == 0) ? 1.f : 0.f;
    int ohB = ohA - 1, owB = owA - 1;
    int ohAc = (ohA < OH) ? ohA : 0;  int owAc = (owA < OW) ? owA : 0;
    int ohBc = (ohB >= 0) ? ohB : 0;  int owBc = (owB >= 0) ? owB : 0;

    int oAA = ohAc*OW + owAc; float mAA = mhA*mwA; int kAA = kh0*3 + kw0;
    int oAB = ohAc*OW + owBc; float mAB = mhA*mwB; int kAB = kh0*3 + kw0 + 2;
    int oBA = ohBc*OW + owAc; float mBA = mhB*mwA; int kBA = (kh0+2)*3 + kw0;
    int oBB = ohBc*OW + owBc; float mBB = mhB*mwB; int kBB = (kh0+2)*3 + kw0 + 2;

    const float* dzp = dzbuf + (long)b * ATOT + dz_off;
    float acc[ICG];
    #pragma unroll
    for (int g = 0; g < ICG; ++g) acc[g] = 0.f;

    for (int oc = 0; oc < OC; ++oc) {
        const float* dzo = dzp + oc * OHW;
        float dAA = dzo[oAA] * mAA;
        float dAB = dzo[oAB] * mAB;
        float dBA = dzo[oBA] * mBA;
        float dBB = dzo[oBB] * mBB;
        const float* w = wlds + oc * 9 * ICG;
        #pragma unroll
        for (int g = 0; g < ICG; ++g)
            acc[g] += dAA * w[kAA*ICG+g] + dAB * w[kAB*ICG+g]
                    + dBA * w[kBA*ICG+g] + dBB * w[kBB*ICG+g];
    }
    #pragma unroll
    for (int g = 0; g < ICG; ++g) {
        long p = (long)b * ATOT + (long)(ic0 + g) * IHW + pix;
        float a = ain[p + ain_off];
        dzin[p + dzin_off] = (a > 0.f) ? acc[g] : 0.f;
    }
}

// ---------------- conv backward dW+db: one wave per (b, oc, ic) ----------------
template<int IC,int IH,int IW,int OC,int OH,int OW,int S>
__global__ __launch_bounds__(64) void conv_bwd_dw2(
    float* __restrict__ fw, int woff, int boff,
    const float* __restrict__ dzbuf, int dz_off,
    const float* __restrict__ xb, long x_ts,
    const float* __restrict__ loglr)
{
    constexpr int OHW = OH*OW;
    int bi = blockIdx.x;
    int ic = bi % IC; int oc = (bi / IC) % OC; int b = bi / (IC * OC);
    int lane = threadIdx.x;
    const float* dzp = dzbuf + (long)b * ATOT + dz_off + (long)oc * OHW;
    const float* xp  = xb + (long)b * x_ts + (long)ic * IH * IW;

    float acc[10];
    #pragma unroll
    for (int k = 0; k < 10; ++k) acc[k] = 0.f;

    for (int pos = lane; pos < OHW; pos += 64) {
        float dzv = dzp[pos];
        int oh = pos / OW, ow = pos % OW;
        int ihb = oh * S - 1, iwb = ow * S - 1;
        acc[9] += dzv;
        #pragma unroll
        for (int kh = 0; kh < 3; ++kh) {
            int ih = ihb + kh;
            bool hv = ((unsigned)ih < (unsigned)IH);
            #pragma unroll
            for (int kw = 0; kw < 3; ++kw) {
                int iw = iwb + kw;
                float xv = (hv && (unsigned)iw < (unsigned)IW) ? xp[ih * IW + iw] : 0.f;
                acc[kh*3+kw] += dzv * xv;
            }
        }
    }
    #pragma unroll
    for (int k = 0; k < 10; ++k)
        for (int off = 32; off; off >>= 1) acc[k] += __shfl_down(acc[k], off, 64);

    if (lane == 0) {
        float lr = expf(loglr[0]);
        float* wp = fw + (long)b * PT + woff + ((long)oc * IC + ic) * 9;
        #pragma unroll
        for (int k = 0; k < 9; ++k) wp[k] -= lr * acc[k];
        if (ic == 0) fw[(long)b * PT + boff + oc] -= lr * acc[9];
    }
}

// ---------------- old dW/db (layer 4: tiny spatial) ----------------
__global__ void conv_bwd_dw(float* __restrict__ fw, int woff,
                            const float* __restrict__ dz, long dz_off,
                            const float* __restrict__ xb, long x_ts,
                            const float* __restrict__ loglr,
                            int IC, int IH, int IW, int OC, int OH, int OW, int s)
{
    long idx = (long)blockIdx.x * blockDim.x + threadIdx.x;
    long total = (long)NB * OC * IC * 9;
    if (idx >= total) return;
    int k = (int)(idx % 9); int kw = k % 3, kh = k / 3;
    long r = idx / 9; int ic = (int)(r % IC); r /= IC;
    int oc = (int)(r % OC); int b = (int)(r / OC);
    const float* dzp = dz + (long)b * ATOT + dz_off + (long)oc * OH * OW;
    const float* x = xb + (long)b * x_ts + (long)ic * IH * IW;
    float acc = 0.f;
    for (int oh = 0; oh < OH; ++oh) {
        int ih = oh * s - 1 + kh;
        if (ih < 0 || ih >= IH) continue;
        for (int ow = 0; ow < OW; ++ow) {
            int iw = ow * s - 1 + kw;
            if (iw < 0 || iw >= IW) continue;
            acc += dzp[oh * OW + ow] * x[ih * IW + iw];
        }
    }
    fw[(long)b * PT + woff + ((long)(oc * IC + ic) * 3 + kh) * 3 + kw] -= expf(loglr[0]) * acc;
}

__global__ void conv_bwd_db(float* __restrict__ fw, int boff,
                            const float* __restrict__ dz, long dz_off,
                            const float* __restrict__ loglr, int OC, int OH, int OW)
{
    int idx = blockIdx.x * blockDim.x + threadIdx.x;
    if (idx >= NB * OC) return;
    int oc = idx % OC, b = idx / OC;
    const float* p = dz + (long)b * ATOT + dz_off + (long)oc * OH * OW;
    float acc = 0.f;
    for (int i = 0; i < OH * OW; ++i) acc += p[i];
    fw[(long)b * PT + boff + oc] -= expf(loglr[0]) * acc;
}

// ---------------- final loss / eval ----------------
__global__ void final_loss_eval(const float* __restrict__ logit_base,
                                const int* __restrict__ test_y,
                                float* __restrict__ out, int l0, int Lc)
{
    int idx = blockIdx.x * blockDim.x + threadIdx.x;
    if (idx >= NB * Lc) return;
    int n = idx % Lc, b = idx / Lc;
    int l = l0 + n;
    const float* lo = logit_base + ((long)b * NL + l) * NCLS;
    float mx = -1e30f; int am = 0;
    for (int c = 0; c < NCLS; ++c) { float v = lo[c]; if (v > mx) { mx = v; am = c; } }
    float se = 0.f;
    for (int c = 0; c < NCLS; ++c) se += expf(lo[c] - mx);
    int y = test_y[b * NL + l];
    out[b * NL + l] = -(lo[y] - mx - logf(se));
    out[129 + b * NL + l] = (am == y) ? 1.f : 0.f;
}

__global__ void write_lr(const float* __restrict__ loglr, float* __restrict__ out)
{
    if (threadIdx.x == 0 && blockIdx.x == 0) out[128] = expf(loglr[0]);
}

// ---------------- host orchestration ----------------
extern "C" void kernel_launch(void* const* d_in, const int* in_sizes, int n_in,
                              void* d_out, int out_size, void* d_ws, size_t ws_size,
                              hipStream_t stream)
{
    const float* loglr      = (const float*)d_in[12];
    const float* train_x    = (const float*)d_in[13];
    const float* test_x     = (const float*)d_in[14];
    const float* train_gate = (const float*)d_in[15];
    const float* test_gate  = (const float*)d_in[16];
    const int*   train_y    = (const int*)d_in[17];
    const int*   test_y     = (const int*)d_in[18];
    float* out = (float*)d_out;

    // ---- choose test-chunk size LCr from workspace budget (constant per run) ----
    const long base = (long)NB*PT + 2L*NB*ATOT + 2L*NB*NCLS;
    int LCr = 4;
    if (ws_size >= (size_t)(base + 16L*1572864) * 4) LCr = 16;
    else if (ws_size >= (size_t)(base + 8L*1572864) * 4) LCr = 8;

    float* ws   = (float*)d_ws;
    float* FWp  = ws;
    float* AINp = FWp  + (long)NB * PT;
    float* DZp  = AINp + (long)NB * ATOT;
    float* LOGIp= DZp  + (long)NB * ATOT;
    float* DLOGp= LOGIp + NB * NCLS;
    float* TAp  = DLOGp + NB * NCLS;
    float* TBp  = TAp + (long)NB * LCr * 131072;

    Params12 ps;
    for (int j = 0; j < 12; ++j) ps.p[j] = (const float*)d_in[j];
    {
        long tot = (long)NB * PT;
        bcast_kernel<<<(int)((tot + 255) / 256), 256, 0, stream>>>(ps, FWp);
    }

    for (int t = 0; t < NT; ++t) {
        // ---- forward convs (train): conv_fwd mapping, UF-blocked loads ----
        conv_fwd_u<3,64,64,32,64,64,1,3,256><<<4096, 256, 0, stream>>>(
            train_x + (long)t * CHW, (long)NT * CHW, FWp, OFF_W0, OFF_B0, AINp + A1, (long)ATOT);
        conv_fwd_u<32,64,64,64,32,32,2,4,256><<<2048, 256, 0, stream>>>(
            AINp + A1, (long)ATOT, FWp, OFF_W1, OFF_B1, AINp + A2, (long)ATOT);
        conv_fwd_u<64,32,32,128,16,16,2,4,256><<<1024, 256, 0, stream>>>(
            AINp + A2, (long)ATOT, FWp, OFF_W2, OFF_B2, AINp + A3, (long)ATOT);
        // L3/L4: 64-thread blocks spread waves across all CUs (bit-identical mapping)
        conv_fwd_u<128,16,16,256,8,8,2,4,64><<<2048, 64, 0, stream>>>(
            AINp + A3, (long)ATOT, FWp, OFF_W3, OFF_B3, AINp + A4, (long)ATOT);
        conv_fwd_u<256,8,8,256,4,4,2,8,64><<<512, 64, 0, stream>>>(
            AINp + A4, (long)ATOT, FWp, OFF_W4, OFF_B4, AINp + A5, (long)ATOT);

        {
            long waves = (long)NB * NCLS;
            head_fwd<<<(int)((waves * 64 + 255) / 256), 256, 0, stream>>>(
                AINp + A5, (long)ATOT, 0,
                train_gate + (long)t * FEAT, (long)NT * FEAT, 0,
                FWp, LOGIp, (long)NCLS, 0, 1);
        }
        softmax_dlogit<<<NB, 128, 0, stream>>>(LOGIp, train_y, t, DLOGp);
        head_bwd_dz5<<<(NB * FEAT + 255) / 256, 256, 0, stream>>>(
            FWp, DLOGp, AINp, train_gate + (long)t * FEAT, (long)NT * FEAT, DZp);
        {
            long tot = (long)NB * NCLS * FEAT;
            head_update<<<(int)((tot + 255) / 256), 256, 0, stream>>>(
                FWp, DLOGp, AINp, train_gate + (long)t * FEAT, (long)NT * FEAT, loglr);
        }

        // ---- backward chain (r9-exact, FROZEN) ----
        conv_bwd_dx2<256,8,8,256,4,4,2,64><<<8*128, 64, 0, stream>>>(
            DZp, A5, FWp, OFF_W4, AINp, A4, DZp, A4);
        {
            long totw = (long)NB * 256 * 256 * 9;
            conv_bwd_dw<<<(int)((totw + 255) / 256), 256, 0, stream>>>(
                FWp, OFF_W4, DZp, A5, AINp + A4, (long)ATOT, loglr,
                256, 8, 8, 256, 4, 4, 2);
            conv_bwd_db<<<(NB * 256 + 255) / 256, 256, 0, stream>>>(
                FWp, OFF_B4, DZp, A5, loglr, 256, 4, 4);
        }
        conv_bwd_dx2<128,16,16,256,8,8,4,256><<<8*32, 256, 0, stream>>>(
            DZp, A4, FWp, OFF_W3, AINp, A3, DZp, A3);
        conv_bwd_dw2<128,16,16,256,8,8,2><<<8*256*128, 64, 0, stream>>>(
            FWp, OFF_W3, OFF_B3, DZp, A4, AINp + A3, (long)ATOT, loglr);
        conv_bwd_dx2<64,32,32,128,16,16,4,256><<<8*16*4, 256, 0, stream>>>(
            DZp, A3, FWp, OFF_W2, AINp, A2, DZp, A2);
        conv_bwd_dw2<64,32,32,128,16,16,2><<<8*128*64, 64, 0, stream>>>(
            FWp, OFF_W2, OFF_B2, DZp, A3, AINp + A2, (long)ATOT, loglr);
        conv_bwd_dx2<32,64,64,64,32,32,4,256><<<8*8*16, 256, 0, stream>>>(
            DZp, A2, FWp, OFF_W1, AINp, A1, DZp, A1);
        conv_bwd_dw2<32,64,64,64,32,32,2><<<8*64*32, 64, 0, stream>>>(
            FWp, OFF_W1, OFF_B1, DZp, A2, AINp + A1, (long)ATOT, loglr);
        conv_bwd_dw2<3,64,64,32,64,64,1><<<8*32*3, 64, 0, stream>>>(
            FWp, OFF_W0, OFF_B0, DZp, A1, train_x + (long)t * CHW, (long)NT * CHW, loglr);
    }

    // 3) test forward
    if (LCr == 16) {
        conv_fwd2<3,64,64,32,64,64,1, 32,1,3><<<NB*16*16, 256, 0, stream>>>(
            test_x, (long)NL * CHW, CHW,
            FWp, OFF_W0, OFF_B0, TAp, 16L * 131072, 16);
        conv_fwd2<32,64,64,64,32,32,2, 16,1,8><<<NB*16*16, 256, 0, stream>>>(
            TAp, 16L * 131072, 131072,
            FWp, OFF_W1, OFF_B1, TBp, 16L * 65536, 16);
        conv_fwd2<64,32,32,128,16,16,2, 16,1,8><<<NB*16*8, 256, 0, stream>>>(
            TBp, 16L * 65536, 65536,
            FWp, OFF_W2, OFF_B2, TAp, 16L * 32768, 16);
        // L3: flattened-n, TOC=16, ICB=8 (r9/r13 proven) -> grid 8*4*16 = 512
        conv_fwd2b<128,16,16,256,8,8,2, 16,8,16><<<NB*4*16, 256, 0, stream>>>(
            TAp, 16L * 32768, 32768,
            FWp, OFF_W3, OFF_B3, TBp, 16L * 16384);
        // L4: flattened-n, TOC=16, ICB=8 (r9/r13 proven) -> grid 8*16 = 128
        conv_fwd2b<256,8,8,256,4,4,2, 16,8,16><<<NB*16, 256, 0, stream>>>(
            TBp, 16L * 16384, 16384,
            FWp, OFF_W4, OFF_B4, TAp, 16L * 4096);
        {
            long waves = (long)NB * 16 * NCLS;
            head_fwd<<<(int)((waves * 64 + 255) / 256), 256, 0, stream>>>(
                TAp, 16L * FEAT, FEAT,
                test_gate, (long)NL * FEAT, FEAT,
                FWp, out + 257, (long)NL * NCLS, NCLS, 16);
        }
    } else {
        for (int c = 0; c < NL / LCr; ++c) {
            int l0 = c * LCr;
            conv_fwd2<3,64,64,32,64,64,1, 32,1,3><<<NB*LCr*16, 256, 0, stream>>>(
                test_x + (long)l0 * CHW, (long)NL * CHW, CHW,
                FWp, OFF_W0, OFF_B0, TAp, (long)LCr * 131072, LCr);
            conv_fwd2<32,64,64,64,32,32,2, 16,1,8><<<NB*LCr*16, 256, 0, stream>>>(
                TAp, (long)LCr * 131072, 131072,
                FWp, OFF_W1, OFF_B1, TBp, (long)LCr * 65536, LCr);
            conv_fwd2<64,32,32,128,16,16,2, 16,1,8><<<NB*LCr*8, 256, 0, stream>>>(
                TBp, (long)LCr * 65536, 65536,
                FWp, OFF_W2, OFF_B2, TAp, (long)LCr * 32768, LCr);
            conv_fwd2<128,16,16,256,8,8,2, 8,4,8><<<NB*LCr*8, 256, 0, stream>>>(
                TAp, (long)LCr * 32768, 32768,
                FWp, OFF_W3, OFF_B3, TBp, (long)LCr * 16384, LCr);
            conv_fwd2<256,8,8,256,4,4,2, 4,16,8><<<NB*LCr*4, 256, 0, stream>>>(
                TBp, (long)LCr * 16384, 16384,
                FWp, OFF_W4, OFF_B4, TAp, (long)LCr * 4096, LCr);
            {
                long waves = (long)NB * LCr * NCLS;
                head_fwd<<<(int)((waves * 64 + 255) / 256), 256, 0, stream>>>(
                    TAp, (long)LCr * FEAT, FEAT,
                    test_gate + (long)l0 * FEAT, (long)NL * FEAT, FEAT,
                    FWp, out + 257 + (long)l0 * NCLS, (long)NL * NCLS, NCLS, LCr);
            }
        }
    }
    final_loss_eval<<<(NB * NL + 255) / 256, 256, 0, stream>>>(
        out + 257, test_y, out, 0, NL);
    write_lr<<<1, 1, 0, stream>>>(loglr, out);
}